// Round 9
// baseline (488.321 us; speedup 1.0000x reference)
//
#include <hip/hip_runtime.h>
#include <hip/hip_cooperative_groups.h>
#include <math.h>

namespace cg = cooperative_groups;

#define N_NODES 20000
#define N_EDGES 160000

#define COOP_BLOCKS 512
#define COOP_NT (COOP_BLOCKS * 256)

// ws layout (bytes). ~25 MB.
static const size_t OFF_EF  = 0;                                    // ef [E][36] f32 (CSR-ordered rows)
static const size_t OFF_T   = OFF_EF  + (size_t)N_EDGES * 36 * 4;   // T [100][64][12] f32
static const size_t OFF_W1T = OFF_T   + (size_t)100 * 64 * 12 * 4;  // w1T [64][16]
static const size_t OFF_W2T = OFF_W1T + (size_t)64 * 16 * 4;        // w2T [64][64]
static const size_t OFF_W3T = OFF_W2T + (size_t)64 * 64 * 4;        // w3T [64][64]
static const size_t OFF_NOFF= OFF_W3T + (size_t)64 * 64 * 4;        // node_off [N+1] int
static const size_t OFF_NCNT= OFF_NOFF+ (size_t)(N_NODES + 1) * 4;  // cnt_i [N] int
static const size_t OFF_NCUR= OFF_NCNT+ (size_t)N_NODES * 4;        // node_cur [N] int
static const size_t OFF_CSR = OFF_NCUR+ (size_t)N_NODES * 4;        // csr_edges [E] int

__device__ __forceinline__ float silu_f(float x) {
    return x / (1.0f + __expf(-x));
}

// ---------------- K1 (cooperative): zero+transposes+ai/T -> hist -> scan -> scatter --
__global__ __launch_bounds__(256, 4) void csr_prep_kernel(
        const float* __restrict__ emb,
        const float* __restrict__ fw1, const float* __restrict__ fb1,
        const float* __restrict__ fw2, const float* __restrict__ fb2,
        const float* __restrict__ fw3, const float* __restrict__ fb3,
        const float* __restrict__ fc_w1, const float* __restrict__ fc_w2,
        const float* __restrict__ fc_w3, const float* __restrict__ fc_w4,
        const int* __restrict__ edst,
        float* __restrict__ w1t, float* __restrict__ w2t,
        float* __restrict__ w3t, float* __restrict__ T,
        int* __restrict__ cnt_i, int* __restrict__ node_cur,
        int* __restrict__ node_off, int* __restrict__ csr_edges) {
    cg::grid_group grid = cg::this_grid();
    __shared__ float aismem[1040];      // h1s[640] | h2s[320] | ai[80]
    __shared__ int   part[256];         // scan partials (block 0)
    int tid = threadIdx.x;
    int bid = blockIdx.x;
    int gtid = bid * 256 + tid;

    // ---- Phase A: zero counters; weight transposes; ai-table + T build -------------
    for (int i = gtid; i < N_NODES; i += COOP_NT) { cnt_i[i] = 0; node_cur[i] = 0; }

    if (gtid < 1024) {
        int j = gtid >> 4, i = gtid & 15;
        w1t[j * 16 + i] = fc_w1[i * 64 + j];
    } else if (gtid < 5120) {
        int t = gtid - 1024; int j = t >> 6, i = t & 63;
        w2t[j * 64 + i] = fc_w2[i * 64 + j];
    } else if (gtid < 9216) {
        int t = gtid - 5120; int j = t >> 6, i = t & 63;
        w3t[j * 64 + i] = fc_w3[i * 64 + j];
    }

    if (bid >= 64 && bid < 89) {
        // inline node-type MLP (redundant per block, tiny)
        float* h1s = aismem;            // [10][64]
        float* h2s = aismem + 640;      // [10][32]
        float* ai  = aismem + 960;      // [10][8]
        for (int idx = tid; idx < 640; idx += 256) {
            int t = idx >> 6, j = idx & 63;
            float acc = fb1[j];
            #pragma unroll
            for (int i = 0; i < 16; i++) acc += emb[t * 16 + i] * fw1[i * 64 + j];
            h1s[idx] = silu_f(acc);
        }
        __syncthreads();
        for (int idx = tid; idx < 320; idx += 256) {
            int t = idx >> 5, j = idx & 31;
            float acc = fb2[j];
            #pragma unroll
            for (int i = 0; i < 64; i++) acc += h1s[t * 64 + i] * fw2[i * 32 + j];
            h2s[idx] = silu_f(acc);
        }
        __syncthreads();
        if (tid < 80) {
            int t = tid >> 3, j = tid & 7;
            float acc = fb3[j];
            #pragma unroll
            for (int i = 0; i < 32; i++) acc += h2s[t * 32 + i] * fw3[i * 8 + j];
            ai[tid] = acc;
        }
        __syncthreads();

        // T[pair][k][12] build: 25 blocks x 256 threads = 6400 = 100 pairs x 64 k
        int idx = (bid - 64) * 256 + tid;
        int pair = idx >> 6;
        int k = idx & 63;
        int ts = pair / 10, td = pair - ts * 10;
        float a[8], bb[8];
        #pragma unroll
        for (int i = 0; i < 8; i++) a[i] = ai[ts * 8 + i];
        #pragma unroll
        for (int i = 0; i < 8; i++) bb[i] = ai[td * 8 + i];
        float sv[12];
        #pragma unroll
        for (int i = 0; i < 12; i++) sv[i] = 0.0f;
        const float* wk = fc_w4 + k * 768;
        #pragma unroll 2
        for (int u = 0; u < 8; u++) {
            #pragma unroll
            for (int v = 0; v < 8; v++) {
                float ab = a[u] * bb[v];
                const float* wp = wk + u * 32 + v * 4;
                float4 w0 = *(const float4*)(wp);
                float4 w1 = *(const float4*)(wp + 256);
                float4 w2 = *(const float4*)(wp + 512);
                sv[0] += ab * w0.x; sv[1] += ab * w0.y; sv[2]  += ab * w0.z; sv[3]  += ab * w0.w;
                sv[4] += ab * w1.x; sv[5] += ab * w1.y; sv[6]  += ab * w1.z; sv[7]  += ab * w1.w;
                sv[8] += ab * w2.x; sv[9] += ab * w2.y; sv[10] += ab * w2.z; sv[11] += ab * w2.w;
            }
        }
        float* tp = T + pair * 768 + k * 12;
        #pragma unroll
        for (int j = 0; j < 12; j++) tp[j] = sv[j];
    }
    grid.sync();

    // ---- Phase B: histogram ---------------------------------------------------------
    for (int e = gtid; e < N_EDGES; e += COOP_NT) atomicAdd(&cnt_i[edst[e]], 1);
    grid.sync();

    // ---- Phase C: exclusive scan (block 0; 256 threads x 79 nodes) -----------------
    if (bid == 0) {
        int base = tid * 79;
        int s = 0;
        for (int i = 0; i < 79; i++) {
            int n = base + i;
            if (n < N_NODES) s += cnt_i[n];
        }
        part[tid] = s;
        __syncthreads();
        for (int off = 1; off < 256; off <<= 1) {
            int v = part[tid];
            int add = (tid >= off) ? part[tid - off] : 0;
            __syncthreads();
            part[tid] = v + add;
            __syncthreads();
        }
        int run = (tid == 0) ? 0 : part[tid - 1];
        for (int i = 0; i < 79; i++) {
            int n = base + i;
            if (n < N_NODES) { node_off[n] = run; run += cnt_i[n]; }
        }
        if (tid == 255) node_off[N_NODES] = part[255];
    }
    grid.sync();

    // ---- Phase D: scatter edge ids into CSR ----------------------------------------
    for (int e = gtid; e < N_EDGES; e += COOP_NT) {
        int d = edst[e];
        int slot = atomicAdd(&node_cur[d], 1);
        csr_edges[node_off[d] + slot] = e;
    }
}

// ---------------- K2: cooperative fused edge kernel, CSR-ordered output (r7) --------
__global__ __launch_bounds__(256) void edge_fused_kernel(
        const float* __restrict__ pos, const int* __restrict__ batch,
        const int* __restrict__ esrc, const int* __restrict__ edst,
        const float* __restrict__ shifts, const float* __restrict__ cell,
        const int* __restrict__ A, const int* __restrict__ csr_edges,
        const float* __restrict__ w1t, const float* __restrict__ w2t,
        const float* __restrict__ w3t, const float* __restrict__ T,
        float* __restrict__ ef) {
    __shared__ float smem[4096];
    int tid = threadIdx.x;
    int lane = tid & 63;
    int wq = __builtin_amdgcn_readfirstlane(tid >> 6);
    int p = blockIdx.x * 64 + lane;
    int e = csr_edges[p];

    int s = esrc[e], d = edst[e];
    int gb = batch[s];
    float t0 = shifts[e * 3 + 0], t1 = shifts[e * 3 + 1], t2 = shifts[e * 3 + 2];
    const float* C = cell + gb * 9;
    float shx = t0 * C[0] + t1 * C[3] + t2 * C[6];
    float shy = t0 * C[1] + t1 * C[4] + t2 * C[7];
    float shz = t0 * C[2] + t1 * C[5] + t2 * C[8];
    float ex = pos[d * 3 + 0] - pos[s * 3 + 0] + shx;
    float ey = pos[d * 3 + 1] - pos[s * 3 + 1] + shy;
    float ez = pos[d * 3 + 2] - pos[s * 3 + 2] + shz;
    float r = sqrtf(ex * ex + ey * ey + ez * ez);
    float inv = 1.0f / fmaxf(r, 1e-9f);
    float x = ex * inv, y = ey * inv, z = ez * inv;

    float rb[16];
    const float step = 5.0f / 17.0f;
    const float istep = 17.0f / 5.0f;
    const float rsc = 4.0f / 1.12f;
    #pragma unroll
    for (int i = 0; i < 16; i++) {
        float dd = (r - (float)(i + 1) * step) * istep;
        rb[i] = __expf(-dd * dd) * rsc;
    }

    // L1: 16 -> 64
    #pragma unroll
    for (int jj = 0; jj < 16; jj++) {
        const float* wr = w1t + (wq * 16 + jj) * 16;
        float a0 = 0, a1 = 0, a2 = 0, a3 = 0;
        #pragma unroll
        for (int i = 0; i < 16; i += 4) {
            a0 += rb[i] * wr[i];         a1 += rb[i + 1] * wr[i + 1];
            a2 += rb[i + 2] * wr[i + 2]; a3 += rb[i + 3] * wr[i + 3];
        }
        smem[(wq * 16 + jj) * 64 + lane] = silu_f(((a0 + a1) + (a2 + a3)) * 0.25f);
    }
    __syncthreads();

    // L2: 64 -> 64
    float acc[16];
    #pragma unroll
    for (int jj = 0; jj < 16; jj++) acc[jj] = 0.0f;
    #pragma unroll
    for (int c = 0; c < 4; c++) {
        float hc[16];
        #pragma unroll
        for (int i = 0; i < 16; i++) hc[i] = smem[(c * 16 + i) * 64 + lane];
        #pragma unroll
        for (int jj = 0; jj < 16; jj++) {
            const float* wr = w2t + (wq * 16 + jj) * 64 + c * 16;
            #pragma unroll
            for (int i = 0; i < 16; i++) acc[jj] += hc[i] * wr[i];
        }
    }
    float hn[16];
    #pragma unroll
    for (int jj = 0; jj < 16; jj++) hn[jj] = silu_f(acc[jj] * 0.125f);
    __syncthreads();
    #pragma unroll
    for (int jj = 0; jj < 16; jj++) smem[(wq * 16 + jj) * 64 + lane] = hn[jj];
    __syncthreads();

    // L3 fused with T-matvec
    #pragma unroll
    for (int jj = 0; jj < 16; jj++) acc[jj] = 0.0f;
    #pragma unroll
    for (int c = 0; c < 4; c++) {
        float hc[16];
        #pragma unroll
        for (int i = 0; i < 16; i++) hc[i] = smem[(c * 16 + i) * 64 + lane];
        #pragma unroll
        for (int jj = 0; jj < 16; jj++) {
            const float* wr = w3t + (wq * 16 + jj) * 64 + c * 16;
            #pragma unroll
            for (int i = 0; i < 16; i++) acc[jj] += hc[i] * wr[i];
        }
    }
    float gk[16];
    #pragma unroll
    for (int jj = 0; jj < 16; jj++) gk[jj] = silu_f(acc[jj] * 0.125f);

    int pair = A[s] * 10 + A[d];
    const float* Tp = T + pair * 768 + wq * 16 * 12;

    float sv[12];
    #pragma unroll
    for (int i = 0; i < 12; i++) sv[i] = 0.0f;
    #pragma unroll
    for (int jj = 0; jj < 16; jj++) {
        const float* tp = Tp + jj * 12;
        float4 q0 = *(const float4*)(tp);
        float4 q1 = *(const float4*)(tp + 4);
        float4 q2 = *(const float4*)(tp + 8);
        float g = gk[jj];
        sv[0] += g * q0.x; sv[1] += g * q0.y; sv[2]  += g * q0.z; sv[3]  += g * q0.w;
        sv[4] += g * q1.x; sv[5] += g * q1.y; sv[6]  += g * q1.z; sv[7]  += g * q1.w;
        sv[8] += g * q2.x; sv[9] += g * q2.y; sv[10] += g * q2.z; sv[11] += g * q2.w;
    }
    __syncthreads();

    #pragma unroll
    for (int j = 0; j < 12; j++) smem[(wq * 12 + j) * 64 + lane] = sv[j];
    __syncthreads();

    float s0 = 0.0f, s1 = 0.0f, s2 = 0.0f;
    #pragma unroll
    for (int q = 0; q < 4; q++) {
        s0 += smem[(q * 12 + wq + 0) * 64 + lane];
        s1 += smem[(q * 12 + wq + 4) * 64 + lane];
        s2 += smem[(q * 12 + wq + 8) * 64 + lane];
    }
    const float isc = 1.0f / 64.0f;
    s0 *= isc; s1 *= isc; s2 *= isc;

    const float S3  = 1.7320508075688772f;
    const float S15 = 3.8729833462074170f;
    const float S5  = 2.2360679774997896f;
    float sh1v[3], sh2v[5];
    sh1v[0] = S3 * y; sh1v[1] = S3 * z; sh1v[2] = S3 * x;
    sh2v[0] = S15 * x * y;
    sh2v[1] = S15 * y * z;
    sh2v[2] = 0.5f * S5 * (3.0f * z * z - 1.0f);
    sh2v[3] = S15 * x * z;
    sh2v[4] = 0.5f * S15 * (x * x - y * y);

    float* o = ef + (size_t)p * 36;
    o[wq] = s0;
    #pragma unroll
    for (int jj = 0; jj < 3; jj++) o[4 + wq * 3 + jj] = s1 * sh1v[jj];
    #pragma unroll
    for (int jj = 0; jj < 5; jj++) o[16 + wq * 5 + jj] = s2 * sh2v[jj];
}

// ---------------- K3: gather + mean (float4 stream per node) -------------------------
__global__ void gather_kernel(const float* __restrict__ ef,
                              const int* __restrict__ node_off,
                              float* __restrict__ out) {
    int idx = blockIdx.x * 256 + threadIdx.x;   // (node, float4-group)
    if (idx >= N_NODES * 9) return;
    int n = idx / 9;
    int g = idx - n * 9;
    int beg = node_off[n], end = node_off[n + 1];
    const float4* ef4 = (const float4*)ef;
    float4 s = make_float4(0.f, 0.f, 0.f, 0.f);
    for (int p = beg; p < end; p++) {
        float4 v = ef4[(size_t)p * 9 + g];
        s.x += v.x; s.y += v.y; s.z += v.z; s.w += v.w;
    }
    float c = 1.0f / fmaxf((float)(end - beg), 1.0f);
    float4 r = make_float4(s.x * c, s.y * c, s.z * c, s.w * c);
    ((float4*)out)[idx] = r;
}

extern "C" void kernel_launch(void* const* d_in, const int* in_sizes, int n_in,
                              void* d_out, int out_size, void* d_ws, size_t ws_size,
                              hipStream_t stream) {
    const float* pos    = (const float*)d_in[0];
    const int*   A      = (const int*)d_in[1];
    const int*   batch  = (const int*)d_in[2];
    const int*   esrc   = (const int*)d_in[3];
    const int*   edst   = (const int*)d_in[4];
    const float* shifts = (const float*)d_in[5];
    const float* cell   = (const float*)d_in[6];
    const float* emb    = (const float*)d_in[7];
    const float* fw1    = (const float*)d_in[8];
    const float* fb1    = (const float*)d_in[9];
    const float* fw2    = (const float*)d_in[10];
    const float* fb2    = (const float*)d_in[11];
    const float* fw3    = (const float*)d_in[12];
    const float* fb3    = (const float*)d_in[13];
    const float* fcw1   = (const float*)d_in[14];
    const float* fcw2   = (const float*)d_in[15];
    const float* fcw3   = (const float*)d_in[16];
    const float* fcw4   = (const float*)d_in[17];
    float* out = (float*)d_out;

    char* ws = (char*)d_ws;
    float* ef      = (float*)(ws + OFF_EF);
    float* T       = (float*)(ws + OFF_T);
    float* w1t     = (float*)(ws + OFF_W1T);
    float* w2t     = (float*)(ws + OFF_W2T);
    float* w3t     = (float*)(ws + OFF_W3T);
    int*   node_off= (int*)(ws + OFF_NOFF);
    int*   cnt_i   = (int*)(ws + OFF_NCNT);
    int*   node_cur= (int*)(ws + OFF_NCUR);
    int*   csr     = (int*)(ws + OFF_CSR);

    void* args[] = {
        (void*)&emb,
        (void*)&fw1, (void*)&fb1, (void*)&fw2, (void*)&fb2, (void*)&fw3, (void*)&fb3,
        (void*)&fcw1, (void*)&fcw2, (void*)&fcw3, (void*)&fcw4,
        (void*)&edst,
        (void*)&w1t, (void*)&w2t, (void*)&w3t, (void*)&T,
        (void*)&cnt_i, (void*)&node_cur, (void*)&node_off, (void*)&csr
    };
    hipLaunchCooperativeKernel((void*)csr_prep_kernel, dim3(COOP_BLOCKS), dim3(256),
                               args, 0, stream);

    edge_fused_kernel<<<N_EDGES / 64, 256, 0, stream>>>(
        pos, batch, esrc, edst, shifts, cell, A, csr, w1t, w2t, w3t, T, ef);
    gather_kernel<<<(N_NODES * 9 + 255) / 256, 256, 0, stream>>>(ef, node_off, out);
}

// Round 10
// 295.009 us; speedup vs baseline: 1.6553x; 1.6553x over previous
//
#include <hip/hip_runtime.h>
#include <math.h>

#define N_NODES 20000
#define N_EDGES 160000

#define NBINS   4096                 // usable bins; bin 4096 = endpoint r=7.5 (sv=0 there)
#define BINS1   4097                 // rows stored per pair
#define RMAX    7.5f

// ws layout (bytes). ~45 MB.
static const size_t OFF_EF  = 0;                                     // ef [E][36] f32 (CSR order)
static const size_t OFF_T   = OFF_EF  + (size_t)N_EDGES * 36 * 4;    // T [100][64][12]
static const size_t OFF_G   = OFF_T   + (size_t)100 * 64 * 12 * 4;   // g_table [4097][64]
static const size_t OFF_SV  = OFF_G   + (size_t)BINS1 * 64 * 4;      // sv_table [100][4097][12]
static const size_t OFF_NOFF= OFF_SV  + (size_t)100 * BINS1 * 12 * 4;// node_off [N+1] int
static const size_t OFF_NCNT= OFF_NOFF+ (size_t)(N_NODES + 1) * 4;   // cnt_i [N] int (zeroed)
static const size_t OFF_NCUR= OFF_NCNT+ (size_t)N_NODES * 4;         // node_cur [N] int (zeroed)
static const size_t OFF_CSR = OFF_NCUR+ (size_t)N_NODES * 4;         // csr_edges [E] int

// prep1 grid split: [0,25) ai+T build, [25,42) g-table, [42,667) histogram
#define P1_T_BLOCKS  25
#define P1_G_BLOCKS  17
#define P1_H_BLOCKS  625
#define P1_GRID (P1_T_BLOCKS + P1_G_BLOCKS + P1_H_BLOCKS)
// prep2 grid: block 0 scan, blocks [1, 1+100*17) sv build
#define P2_GRID (1 + 100 * 17)

__device__ __forceinline__ float silu_f(float x) {
    return x / (1.0f + __expf(-x));
}

// ---------------- K1: prep1 — ai+T build | g-table | histogram -----------------------
__global__ __launch_bounds__(256) void prep1_kernel(
        const float* __restrict__ emb,
        const float* __restrict__ fw1, const float* __restrict__ fb1,
        const float* __restrict__ fw2, const float* __restrict__ fb2,
        const float* __restrict__ fw3, const float* __restrict__ fb3,
        const float* __restrict__ fc_w1, const float* __restrict__ fc_w2,
        const float* __restrict__ fc_w3, const float* __restrict__ fc_w4,
        const int* __restrict__ edst,
        float* __restrict__ T, float* __restrict__ g_table,
        int* __restrict__ cnt_i) {
    __shared__ float aismem[1040];      // h1s[640] | h2s[320] | ai[80]
    int b = blockIdx.x;
    int tid = threadIdx.x;

    if (b < P1_T_BLOCKS) {
        // ---- inline node-type MLP (10 types) then T[pair][k][12] build (r8-proven) ----
        float* h1s = aismem;
        float* h2s = aismem + 640;
        float* ai  = aismem + 960;
        for (int idx = tid; idx < 640; idx += 256) {
            int t = idx >> 6, j = idx & 63;
            float acc = fb1[j];
            #pragma unroll
            for (int i = 0; i < 16; i++) acc += emb[t * 16 + i] * fw1[i * 64 + j];
            h1s[idx] = silu_f(acc);
        }
        __syncthreads();
        for (int idx = tid; idx < 320; idx += 256) {
            int t = idx >> 5, j = idx & 31;
            float acc = fb2[j];
            #pragma unroll
            for (int i = 0; i < 64; i++) acc += h1s[t * 64 + i] * fw2[i * 32 + j];
            h2s[idx] = silu_f(acc);
        }
        __syncthreads();
        if (tid < 80) {
            int t = tid >> 3, j = tid & 7;
            float acc = fb3[j];
            #pragma unroll
            for (int i = 0; i < 32; i++) acc += h2s[t * 32 + i] * fw3[i * 8 + j];
            ai[tid] = acc;
        }
        __syncthreads();

        int idx = b * 256 + tid;        // 6400 = 100 pairs x 64 k
        int pair = idx >> 6;
        int k = idx & 63;
        int ts = pair / 10, td = pair - ts * 10;
        float a[8], bb[8];
        #pragma unroll
        for (int i = 0; i < 8; i++) a[i] = ai[ts * 8 + i];
        #pragma unroll
        for (int i = 0; i < 8; i++) bb[i] = ai[td * 8 + i];
        float sv[12];
        #pragma unroll
        for (int i = 0; i < 12; i++) sv[i] = 0.0f;
        const float* wk = fc_w4 + k * 768;
        #pragma unroll 2
        for (int u = 0; u < 8; u++) {
            #pragma unroll
            for (int v = 0; v < 8; v++) {
                float ab = a[u] * bb[v];
                const float* wp = wk + u * 32 + v * 4;
                float4 w0 = *(const float4*)(wp);
                float4 w1 = *(const float4*)(wp + 256);
                float4 w2 = *(const float4*)(wp + 512);
                sv[0] += ab * w0.x; sv[1] += ab * w0.y; sv[2]  += ab * w0.z; sv[3]  += ab * w0.w;
                sv[4] += ab * w1.x; sv[5] += ab * w1.y; sv[6]  += ab * w1.z; sv[7]  += ab * w1.w;
                sv[8] += ab * w2.x; sv[9] += ab * w2.y; sv[10] += ab * w2.z; sv[11] += ab * w2.w;
            }
        }
        float* tp = T + pair * 768 + k * 12;
        #pragma unroll
        for (int j = 0; j < 12; j++) tp[j] = sv[j];
    } else if (b < P1_T_BLOCKS + P1_G_BLOCKS) {
        // ---- g_table[bin][64]: full radial MLP per bin (weights wave-uniform s_loads) ----
        int bin = (b - P1_T_BLOCKS) * 256 + tid;
        if (bin > NBINS) return;
        float r = (float)bin * (RMAX / (float)NBINS);

        float rb[16];
        const float step = 5.0f / 17.0f;
        const float istep = 17.0f / 5.0f;
        const float rsc = 4.0f / 1.12f;
        #pragma unroll
        for (int i = 0; i < 16; i++) {
            float dd = (r - (float)(i + 1) * step) * istep;
            rb[i] = __expf(-dd * dd) * rsc;
        }

        float h[64];
        #pragma unroll 2
        for (int j = 0; j < 64; j += 4) {
            float a0 = 0, a1 = 0, a2 = 0, a3 = 0;
            #pragma unroll
            for (int i = 0; i < 16; i++) {
                float v = rb[i];
                const float* wr = fc_w1 + i * 64 + j;
                a0 += v * wr[0]; a1 += v * wr[1]; a2 += v * wr[2]; a3 += v * wr[3];
            }
            h[j] = silu_f(a0 * 0.25f); h[j + 1] = silu_f(a1 * 0.25f);
            h[j + 2] = silu_f(a2 * 0.25f); h[j + 3] = silu_f(a3 * 0.25f);
        }
        float hn[64];
        #pragma unroll 2
        for (int j = 0; j < 64; j += 4) {
            float a0 = 0, a1 = 0, a2 = 0, a3 = 0;
            #pragma unroll 8
            for (int i = 0; i < 64; i++) {
                float v = h[i];
                const float* wr = fc_w2 + i * 64 + j;
                a0 += v * wr[0]; a1 += v * wr[1]; a2 += v * wr[2]; a3 += v * wr[3];
            }
            hn[j] = silu_f(a0 * 0.125f); hn[j + 1] = silu_f(a1 * 0.125f);
            hn[j + 2] = silu_f(a2 * 0.125f); hn[j + 3] = silu_f(a3 * 0.125f);
        }
        float* gout = g_table + (size_t)bin * 64;
        #pragma unroll 2
        for (int j = 0; j < 64; j += 4) {
            float a0 = 0, a1 = 0, a2 = 0, a3 = 0;
            #pragma unroll 8
            for (int i = 0; i < 64; i++) {
                float v = hn[i];
                const float* wr = fc_w3 + i * 64 + j;
                a0 += v * wr[0]; a1 += v * wr[1]; a2 += v * wr[2]; a3 += v * wr[3];
            }
            gout[j] = silu_f(a0 * 0.125f); gout[j + 1] = silu_f(a1 * 0.125f);
            gout[j + 2] = silu_f(a2 * 0.125f); gout[j + 3] = silu_f(a3 * 0.125f);
        }
    } else {
        // ---- histogram of edge_dst ----
        int e = (b - P1_T_BLOCKS - P1_G_BLOCKS) * 256 + tid;
        if (e < N_EDGES) atomicAdd(&cnt_i[edst[e]], 1);
    }
}

// ---------------- K2: prep2 — scan (block 0) | sv_table = (1/64) g @ T --------------
__global__ __launch_bounds__(256) void prep2_kernel(
        const int* __restrict__ cnt_i, int* __restrict__ node_off,
        const float* __restrict__ T, const float* __restrict__ g_table,
        float* __restrict__ sv_table) {
    __shared__ int part[256];
    int b = blockIdx.x;
    int tid = threadIdx.x;

    if (b == 0) {
        int base = tid * 79;            // 256 * 79 >= 20000
        int s = 0;
        for (int i = 0; i < 79; i++) {
            int n = base + i;
            if (n < N_NODES) s += cnt_i[n];
        }
        part[tid] = s;
        __syncthreads();
        for (int off = 1; off < 256; off <<= 1) {
            int v = part[tid];
            int add = (tid >= off) ? part[tid - off] : 0;
            __syncthreads();
            part[tid] = v + add;
            __syncthreads();
        }
        int run = (tid == 0) ? 0 : part[tid - 1];
        for (int i = 0; i < 79; i++) {
            int n = base + i;
            if (n < N_NODES) { node_off[n] = run; run += cnt_i[n]; }
        }
        if (tid == 255) node_off[N_NODES] = part[255];
        return;
    }

    int idx = b - 1;
    int pair = idx / 17;
    int chunk = idx - pair * 17;
    int bin = chunk * 256 + tid;
    if (bin > NBINS) return;

    const float* gp = g_table + (size_t)bin * 64;
    float acc[12];
    #pragma unroll
    for (int j = 0; j < 12; j++) acc[j] = 0.0f;
    const float* Tp = T + pair * 768;
    #pragma unroll 4
    for (int k = 0; k < 64; k++) {
        float g = gp[k];
        const float* tr = Tp + k * 12;         // pair uniform per block -> s_load
        float4 t0 = *(const float4*)(tr);
        float4 t1 = *(const float4*)(tr + 4);
        float4 t2 = *(const float4*)(tr + 8);
        acc[0] += g * t0.x; acc[1] += g * t0.y; acc[2]  += g * t0.z; acc[3]  += g * t0.w;
        acc[4] += g * t1.x; acc[5] += g * t1.y; acc[6]  += g * t1.z; acc[7]  += g * t1.w;
        acc[8] += g * t2.x; acc[9] += g * t2.y; acc[10] += g * t2.z; acc[11] += g * t2.w;
    }
    float* o = sv_table + ((size_t)pair * BINS1 + bin) * 12;
    const float isc = 1.0f / 64.0f;
    #pragma unroll
    for (int j = 0; j < 12; j++) o[j] = acc[j] * isc;
}

// ---------------- K3: scatter edge ids into CSR --------------------------------------
__global__ void scatter_kernel(const int* __restrict__ edst,
                               const int* __restrict__ node_off,
                               int* __restrict__ node_cur,
                               int* __restrict__ csr_edges) {
    int e = blockIdx.x * 256 + threadIdx.x;
    if (e >= N_EDGES) return;
    int d = edst[e];
    int slot = atomicAdd(&node_cur[d], 1);
    csr_edges[node_off[d] + slot] = e;
}

// ---------------- K4: edge kernel — geometry + table lerp + sh epilogue --------------
__global__ __launch_bounds__(256) void edge_table_kernel(
        const float* __restrict__ pos, const int* __restrict__ batch,
        const int* __restrict__ esrc, const int* __restrict__ edst,
        const float* __restrict__ shifts, const float* __restrict__ cell,
        const int* __restrict__ A, const int* __restrict__ csr_edges,
        const float* __restrict__ sv_table, float* __restrict__ ef) {
    int p = blockIdx.x * 256 + threadIdx.x;    // grid exact: 625*256
    int e = csr_edges[p];

    int s = esrc[e], d = edst[e];
    int gb = batch[s];
    float t0 = shifts[e * 3 + 0], t1 = shifts[e * 3 + 1], t2 = shifts[e * 3 + 2];
    const float* C = cell + gb * 9;
    float shx = t0 * C[0] + t1 * C[3] + t2 * C[6];
    float shy = t0 * C[1] + t1 * C[4] + t2 * C[7];
    float shz = t0 * C[2] + t1 * C[5] + t2 * C[8];
    float ex = pos[d * 3 + 0] - pos[s * 3 + 0] + shx;
    float ey = pos[d * 3 + 1] - pos[s * 3 + 1] + shy;
    float ez = pos[d * 3 + 2] - pos[s * 3 + 2] + shz;
    float r = sqrtf(ex * ex + ey * ey + ez * ez);
    float inv = 1.0f / fmaxf(r, 1e-9f);
    float x = ex * inv, y = ey * inv, z = ez * inv;

    float sv[12];
    if (r >= RMAX) {
        #pragma unroll
        for (int j = 0; j < 12; j++) sv[j] = 0.0f;
    } else {
        int pair = A[s] * 10 + A[d];
        float t = r * ((float)NBINS / RMAX);
        int i = (int)t;
        i = (i > NBINS - 1) ? (NBINS - 1) : i;
        float f = t - (float)i;
        const float* r0 = sv_table + ((size_t)pair * BINS1 + i) * 12;  // rows i,i+1 contiguous (96B)
        #pragma unroll
        for (int j = 0; j < 12; j++) {
            float lo = r0[j], hi = r0[12 + j];
            sv[j] = lo + f * (hi - lo);
        }
    }

    const float S3  = 1.7320508075688772f;
    const float S15 = 3.8729833462074170f;
    const float S5  = 2.2360679774997896f;
    float sh1v[3] = { S3 * y, S3 * z, S3 * x };
    float sh2v[5] = { S15 * x * y, S15 * y * z, 0.5f * S5 * (3.0f * z * z - 1.0f),
                      S15 * x * z, 0.5f * S15 * (x * x - y * y) };

    float o[36];
    #pragma unroll
    for (int w = 0; w < 4; w++) o[w] = sv[w];
    #pragma unroll
    for (int w = 0; w < 4; w++) {
        float sw = sv[4 + w];
        #pragma unroll
        for (int j = 0; j < 3; j++) o[4 + w * 3 + j] = sw * sh1v[j];
    }
    #pragma unroll
    for (int w = 0; w < 4; w++) {
        float sw = sv[8 + w];
        #pragma unroll
        for (int j = 0; j < 5; j++) o[16 + w * 5 + j] = sw * sh2v[j];
    }
    float4* dst = (float4*)(ef + (size_t)p * 36);   // 144B = 9 x float4, aligned
    #pragma unroll
    for (int q = 0; q < 9; q++) dst[q] = ((float4*)o)[q];
}

// ---------------- K5: gather + mean (float4 stream per node) -------------------------
__global__ void gather_kernel(const float* __restrict__ ef,
                              const int* __restrict__ node_off,
                              float* __restrict__ out) {
    int idx = blockIdx.x * 256 + threadIdx.x;   // (node, float4-group)
    if (idx >= N_NODES * 9) return;
    int n = idx / 9;
    int g = idx - n * 9;
    int beg = node_off[n], end = node_off[n + 1];
    const float4* ef4 = (const float4*)ef;
    float4 s = make_float4(0.f, 0.f, 0.f, 0.f);
    for (int p = beg; p < end; p++) {
        float4 v = ef4[(size_t)p * 9 + g];
        s.x += v.x; s.y += v.y; s.z += v.z; s.w += v.w;
    }
    float c = 1.0f / fmaxf((float)(end - beg), 1.0f);
    ((float4*)out)[idx] = make_float4(s.x * c, s.y * c, s.z * c, s.w * c);
}

extern "C" void kernel_launch(void* const* d_in, const int* in_sizes, int n_in,
                              void* d_out, int out_size, void* d_ws, size_t ws_size,
                              hipStream_t stream) {
    const float* pos    = (const float*)d_in[0];
    const int*   A      = (const int*)d_in[1];
    const int*   batch  = (const int*)d_in[2];
    const int*   esrc   = (const int*)d_in[3];
    const int*   edst   = (const int*)d_in[4];
    const float* shifts = (const float*)d_in[5];
    const float* cell   = (const float*)d_in[6];
    const float* emb    = (const float*)d_in[7];
    const float* fw1    = (const float*)d_in[8];
    const float* fb1    = (const float*)d_in[9];
    const float* fw2    = (const float*)d_in[10];
    const float* fb2    = (const float*)d_in[11];
    const float* fw3    = (const float*)d_in[12];
    const float* fb3    = (const float*)d_in[13];
    const float* fcw1   = (const float*)d_in[14];
    const float* fcw2   = (const float*)d_in[15];
    const float* fcw3   = (const float*)d_in[16];
    const float* fcw4   = (const float*)d_in[17];
    float* out = (float*)d_out;

    char* ws = (char*)d_ws;
    float* ef      = (float*)(ws + OFF_EF);
    float* T       = (float*)(ws + OFF_T);
    float* g_table = (float*)(ws + OFF_G);
    float* sv_table= (float*)(ws + OFF_SV);
    int*   node_off= (int*)(ws + OFF_NOFF);
    int*   cnt_i   = (int*)(ws + OFF_NCNT);
    int*   node_cur= (int*)(ws + OFF_NCUR);
    int*   csr     = (int*)(ws + OFF_CSR);

    hipMemsetAsync(cnt_i, 0, (size_t)2 * N_NODES * 4, stream);

    prep1_kernel<<<P1_GRID, 256, 0, stream>>>(emb, fw1, fb1, fw2, fb2, fw3, fb3,
                                              fcw1, fcw2, fcw3, fcw4, edst,
                                              T, g_table, cnt_i);
    prep2_kernel<<<P2_GRID, 256, 0, stream>>>(cnt_i, node_off, T, g_table, sv_table);
    scatter_kernel<<<(N_EDGES + 255) / 256, 256, 0, stream>>>(edst, node_off, node_cur, csr);
    edge_table_kernel<<<N_EDGES / 256, 256, 0, stream>>>(
        pos, batch, esrc, edst, shifts, cell, A, csr, sv_table, ef);
    gather_kernel<<<(N_NODES * 9 + 255) / 256, 256, 0, stream>>>(ef, node_off, out);
}

// Round 11
// 215.787 us; speedup vs baseline: 2.2630x; 1.3671x over previous
//
#include <hip/hip_runtime.h>
#include <math.h>

#define N_NODES 20000
#define N_EDGES 160000

#define NBINS   4096                 // usable bins; bin 4096 = endpoint r=7.5 (sv=0 there)
#define BINS1   4097                 // rows stored per pair
#define RMAX    7.5f

// ws layout (bytes). ~45 MB.
static const size_t OFF_EF  = 0;                                     // ef [E][36] f32 (CSR order)
static const size_t OFF_T   = OFF_EF  + (size_t)N_EDGES * 36 * 4;    // T [100][64][12]
static const size_t OFF_G   = OFF_T   + (size_t)100 * 64 * 12 * 4;   // g_tT [64][4097] (k-major)
static const size_t OFF_SV  = OFF_G   + (size_t)64 * BINS1 * 4;      // sv_table [100][4097][12]
static const size_t OFF_NOFF= OFF_SV  + (size_t)100 * BINS1 * 12 * 4;// node_off [N+1] int
static const size_t OFF_NCNT= OFF_NOFF+ (size_t)(N_NODES + 1) * 4;   // cnt_i [N] int (zeroed)
static const size_t OFF_NCUR= OFF_NCNT+ (size_t)N_NODES * 4;         // node_cur [N] int (zeroed)
static const size_t OFF_CSR = OFF_NCUR+ (size_t)N_NODES * 4;         // csr_edges [E] int

// prep1 grid split: [0,25) ai+T build, [25,90) g-table (64 bins/block), [90,715) histogram
#define P1_T_BLOCKS  25
#define P1_G_BLOCKS  65
#define P1_H_BLOCKS  625
#define P1_GRID (P1_T_BLOCKS + P1_G_BLOCKS + P1_H_BLOCKS)
// prep2 grid: block 0 scan, blocks [1, 1+100*17) sv build
#define P2_GRID (1 + 100 * 17)

__device__ __forceinline__ float silu_f(float x) {
    return x / (1.0f + __expf(-x));
}

// ---------------- K1: prep1 — ai+T build | g-table (cooperative) | histogram ---------
__global__ __launch_bounds__(256) void prep1_kernel(
        const float* __restrict__ emb,
        const float* __restrict__ fw1, const float* __restrict__ fb1,
        const float* __restrict__ fw2, const float* __restrict__ fb2,
        const float* __restrict__ fw3, const float* __restrict__ fb3,
        const float* __restrict__ fc_w1, const float* __restrict__ fc_w2,
        const float* __restrict__ fc_w3, const float* __restrict__ fc_w4,
        const int* __restrict__ edst,
        float* __restrict__ T, float* __restrict__ g_tT,
        int* __restrict__ cnt_i) {
    __shared__ float smem[4096];        // T-branch uses 1040; g-branch uses 4096
    int b = blockIdx.x;
    int tid = threadIdx.x;

    if (b < P1_T_BLOCKS) {
        // ---- inline node-type MLP (10 types) then T[pair][k][12] build (r8-proven) ----
        float* h1s = smem;              // [10][64]
        float* h2s = smem + 640;        // [10][32]
        float* ai  = smem + 960;        // [10][8]
        for (int idx = tid; idx < 640; idx += 256) {
            int t = idx >> 6, j = idx & 63;
            float acc = fb1[j];
            #pragma unroll
            for (int i = 0; i < 16; i++) acc += emb[t * 16 + i] * fw1[i * 64 + j];
            h1s[idx] = silu_f(acc);
        }
        __syncthreads();
        for (int idx = tid; idx < 320; idx += 256) {
            int t = idx >> 5, j = idx & 31;
            float acc = fb2[j];
            #pragma unroll
            for (int i = 0; i < 64; i++) acc += h1s[t * 64 + i] * fw2[i * 32 + j];
            h2s[idx] = silu_f(acc);
        }
        __syncthreads();
        if (tid < 80) {
            int t = tid >> 3, j = tid & 7;
            float acc = fb3[j];
            #pragma unroll
            for (int i = 0; i < 32; i++) acc += h2s[t * 32 + i] * fw3[i * 8 + j];
            ai[tid] = acc;
        }
        __syncthreads();

        int idx = b * 256 + tid;        // 6400 = 100 pairs x 64 k
        int pair = idx >> 6;
        int k = idx & 63;
        int ts = pair / 10, td = pair - ts * 10;
        float a[8], bb[8];
        #pragma unroll
        for (int i = 0; i < 8; i++) a[i] = ai[ts * 8 + i];
        #pragma unroll
        for (int i = 0; i < 8; i++) bb[i] = ai[td * 8 + i];
        float sv[12];
        #pragma unroll
        for (int i = 0; i < 12; i++) sv[i] = 0.0f;
        const float* wk = fc_w4 + k * 768;
        #pragma unroll 2
        for (int u = 0; u < 8; u++) {
            #pragma unroll
            for (int v = 0; v < 8; v++) {
                float ab = a[u] * bb[v];
                const float* wp = wk + u * 32 + v * 4;
                float4 w0 = *(const float4*)(wp);
                float4 w1 = *(const float4*)(wp + 256);
                float4 w2 = *(const float4*)(wp + 512);
                sv[0] += ab * w0.x; sv[1] += ab * w0.y; sv[2]  += ab * w0.z; sv[3]  += ab * w0.w;
                sv[4] += ab * w1.x; sv[5] += ab * w1.y; sv[6]  += ab * w1.z; sv[7]  += ab * w1.w;
                sv[8] += ab * w2.x; sv[9] += ab * w2.y; sv[10] += ab * w2.z; sv[11] += ab * w2.w;
            }
        }
        float* tp = T + pair * 768 + k * 12;
        #pragma unroll
        for (int j = 0; j < 12; j++) tp[j] = sv[j];
    } else if (b < P1_T_BLOCKS + P1_G_BLOCKS) {
        // ---- g-table, r7 cooperative structure: 64 bins/block, wave owns 16 channels ----
        int lane = tid & 63;
        int wq = __builtin_amdgcn_readfirstlane(tid >> 6);
        int bin = (b - P1_T_BLOCKS) * 64 + lane;
        bool valid = (bin <= NBINS);
        float r = (float)bin * (RMAX / (float)NBINS);

        float rb[16];
        const float step = 5.0f / 17.0f;
        const float istep = 17.0f / 5.0f;
        const float rsc = 4.0f / 1.12f;
        #pragma unroll
        for (int i = 0; i < 16; i++) {
            float dd = (r - (float)(i + 1) * step) * istep;
            rb[i] = __expf(-dd * dd) * rsc;
        }

        // L1: 16 -> 64 (weight addresses wave-uniform -> scalar loads)
        #pragma unroll
        for (int jj = 0; jj < 16; jj++) {
            int j = wq * 16 + jj;
            float a0 = 0, a1 = 0, a2 = 0, a3 = 0;
            #pragma unroll
            for (int i = 0; i < 16; i += 4) {
                a0 += rb[i]     * fc_w1[(i)     * 64 + j];
                a1 += rb[i + 1] * fc_w1[(i + 1) * 64 + j];
                a2 += rb[i + 2] * fc_w1[(i + 2) * 64 + j];
                a3 += rb[i + 3] * fc_w1[(i + 3) * 64 + j];
            }
            smem[j * 64 + lane] = silu_f(((a0 + a1) + (a2 + a3)) * 0.25f);
        }
        __syncthreads();

        // L2: 64 -> 64
        float acc[16];
        #pragma unroll
        for (int jj = 0; jj < 16; jj++) acc[jj] = 0.0f;
        #pragma unroll
        for (int c = 0; c < 4; c++) {
            float hc[16];
            #pragma unroll
            for (int i = 0; i < 16; i++) hc[i] = smem[(c * 16 + i) * 64 + lane];
            #pragma unroll
            for (int jj = 0; jj < 16; jj++) {
                int j = wq * 16 + jj;
                #pragma unroll
                for (int i = 0; i < 16; i++) acc[jj] += hc[i] * fc_w2[(c * 16 + i) * 64 + j];
            }
        }
        __syncthreads();
        #pragma unroll
        for (int jj = 0; jj < 16; jj++) smem[(wq * 16 + jj) * 64 + lane] = silu_f(acc[jj] * 0.125f);
        __syncthreads();

        // L3: 64 -> 64 -> g_tT[k][bin] (lane-coalesced stores)
        #pragma unroll
        for (int jj = 0; jj < 16; jj++) acc[jj] = 0.0f;
        #pragma unroll
        for (int c = 0; c < 4; c++) {
            float hc[16];
            #pragma unroll
            for (int i = 0; i < 16; i++) hc[i] = smem[(c * 16 + i) * 64 + lane];
            #pragma unroll
            for (int jj = 0; jj < 16; jj++) {
                int j = wq * 16 + jj;
                #pragma unroll
                for (int i = 0; i < 16; i++) acc[jj] += hc[i] * fc_w3[(c * 16 + i) * 64 + j];
            }
        }
        if (valid) {
            #pragma unroll
            for (int jj = 0; jj < 16; jj++)
                g_tT[(size_t)(wq * 16 + jj) * BINS1 + bin] = silu_f(acc[jj] * 0.125f);
        }
    } else {
        // ---- histogram of edge_dst ----
        int e = (b - P1_T_BLOCKS - P1_G_BLOCKS) * 256 + tid;
        if (e < N_EDGES) atomicAdd(&cnt_i[edst[e]], 1);
    }
}

// ---------------- K2: prep2 — scan (block 0) | sv_table = (1/64) g @ T --------------
__global__ __launch_bounds__(256) void prep2_kernel(
        const int* __restrict__ cnt_i, int* __restrict__ node_off,
        const float* __restrict__ T, const float* __restrict__ g_tT,
        float* __restrict__ sv_table) {
    __shared__ int part[256];
    int b = blockIdx.x;
    int tid = threadIdx.x;

    if (b == 0) {
        int base = tid * 79;            // 256 * 79 >= 20000
        int s = 0;
        for (int i = 0; i < 79; i++) {
            int n = base + i;
            if (n < N_NODES) s += cnt_i[n];
        }
        part[tid] = s;
        __syncthreads();
        for (int off = 1; off < 256; off <<= 1) {
            int v = part[tid];
            int add = (tid >= off) ? part[tid - off] : 0;
            __syncthreads();
            part[tid] = v + add;
            __syncthreads();
        }
        int run = (tid == 0) ? 0 : part[tid - 1];
        for (int i = 0; i < 79; i++) {
            int n = base + i;
            if (n < N_NODES) { node_off[n] = run; run += cnt_i[n]; }
        }
        if (tid == 255) node_off[N_NODES] = part[255];
        return;
    }

    int idx = b - 1;
    int pair = idx / 17;
    int chunk = idx - pair * 17;
    int bin = chunk * 256 + tid;
    if (bin > NBINS) return;

    float acc[12];
    #pragma unroll
    for (int j = 0; j < 12; j++) acc[j] = 0.0f;
    const float* Tp = T + pair * 768;
    #pragma unroll 4
    for (int k = 0; k < 64; k++) {
        float g = g_tT[(size_t)k * BINS1 + bin];   // lane-coalesced per k
        const float* tr = Tp + k * 12;             // pair uniform per block -> s_load
        float4 t0 = *(const float4*)(tr);
        float4 t1 = *(const float4*)(tr + 4);
        float4 t2 = *(const float4*)(tr + 8);
        acc[0] += g * t0.x; acc[1] += g * t0.y; acc[2]  += g * t0.z; acc[3]  += g * t0.w;
        acc[4] += g * t1.x; acc[5] += g * t1.y; acc[6]  += g * t1.z; acc[7]  += g * t1.w;
        acc[8] += g * t2.x; acc[9] += g * t2.y; acc[10] += g * t2.z; acc[11] += g * t2.w;
    }
    float* o = sv_table + ((size_t)pair * BINS1 + bin) * 12;
    const float isc = 1.0f / 64.0f;
    #pragma unroll
    for (int j = 0; j < 12; j++) o[j] = acc[j] * isc;
}

// ---------------- K3: scatter edge ids into CSR --------------------------------------
__global__ void scatter_kernel(const int* __restrict__ edst,
                               const int* __restrict__ node_off,
                               int* __restrict__ node_cur,
                               int* __restrict__ csr_edges) {
    int e = blockIdx.x * 256 + threadIdx.x;
    if (e >= N_EDGES) return;
    int d = edst[e];
    int slot = atomicAdd(&node_cur[d], 1);
    csr_edges[node_off[d] + slot] = e;
}

// ---------------- K4: edge kernel — geometry + table lerp + sh epilogue --------------
__global__ __launch_bounds__(256) void edge_table_kernel(
        const float* __restrict__ pos, const int* __restrict__ batch,
        const int* __restrict__ esrc, const int* __restrict__ edst,
        const float* __restrict__ shifts, const float* __restrict__ cell,
        const int* __restrict__ A, const int* __restrict__ csr_edges,
        const float* __restrict__ sv_table, float* __restrict__ ef) {
    int p = blockIdx.x * 256 + threadIdx.x;    // grid exact: 625*256
    int e = csr_edges[p];

    int s = esrc[e], d = edst[e];
    int gb = batch[s];
    float t0 = shifts[e * 3 + 0], t1 = shifts[e * 3 + 1], t2 = shifts[e * 3 + 2];
    const float* C = cell + gb * 9;
    float shx = t0 * C[0] + t1 * C[3] + t2 * C[6];
    float shy = t0 * C[1] + t1 * C[4] + t2 * C[7];
    float shz = t0 * C[2] + t1 * C[5] + t2 * C[8];
    float ex = pos[d * 3 + 0] - pos[s * 3 + 0] + shx;
    float ey = pos[d * 3 + 1] - pos[s * 3 + 1] + shy;
    float ez = pos[d * 3 + 2] - pos[s * 3 + 2] + shz;
    float r = sqrtf(ex * ex + ey * ey + ez * ez);
    float inv = 1.0f / fmaxf(r, 1e-9f);
    float x = ex * inv, y = ey * inv, z = ez * inv;

    float sv[12];
    if (r >= RMAX) {
        #pragma unroll
        for (int j = 0; j < 12; j++) sv[j] = 0.0f;
    } else {
        int pair = A[s] * 10 + A[d];
        float t = r * ((float)NBINS / RMAX);
        int i = (int)t;
        i = (i > NBINS - 1) ? (NBINS - 1) : i;
        float f = t - (float)i;
        const float* r0 = sv_table + ((size_t)pair * BINS1 + i) * 12;  // rows i,i+1 contiguous (96B)
        #pragma unroll
        for (int j = 0; j < 12; j++) {
            float lo = r0[j], hi = r0[12 + j];
            sv[j] = lo + f * (hi - lo);
        }
    }

    const float S3  = 1.7320508075688772f;
    const float S15 = 3.8729833462074170f;
    const float S5  = 2.2360679774997896f;
    float sh1v[3] = { S3 * y, S3 * z, S3 * x };
    float sh2v[5] = { S15 * x * y, S15 * y * z, 0.5f * S5 * (3.0f * z * z - 1.0f),
                      S15 * x * z, 0.5f * S15 * (x * x - y * y) };

    float o[36];
    #pragma unroll
    for (int w = 0; w < 4; w++) o[w] = sv[w];
    #pragma unroll
    for (int w = 0; w < 4; w++) {
        float sw = sv[4 + w];
        #pragma unroll
        for (int j = 0; j < 3; j++) o[4 + w * 3 + j] = sw * sh1v[j];
    }
    #pragma unroll
    for (int w = 0; w < 4; w++) {
        float sw = sv[8 + w];
        #pragma unroll
        for (int j = 0; j < 5; j++) o[16 + w * 5 + j] = sw * sh2v[j];
    }
    float4* dst = (float4*)(ef + (size_t)p * 36);   // 144B = 9 x float4, aligned
    #pragma unroll
    for (int q = 0; q < 9; q++) dst[q] = ((float4*)o)[q];
}

// ---------------- K5: gather + mean (float4 stream per node) -------------------------
__global__ void gather_kernel(const float* __restrict__ ef,
                              const int* __restrict__ node_off,
                              float* __restrict__ out) {
    int idx = blockIdx.x * 256 + threadIdx.x;   // (node, float4-group)
    if (idx >= N_NODES * 9) return;
    int n = idx / 9;
    int g = idx - n * 9;
    int beg = node_off[n], end = node_off[n + 1];
    const float4* ef4 = (const float4*)ef;
    float4 s = make_float4(0.f, 0.f, 0.f, 0.f);
    for (int p = beg; p < end; p++) {
        float4 v = ef4[(size_t)p * 9 + g];
        s.x += v.x; s.y += v.y; s.z += v.z; s.w += v.w;
    }
    float c = 1.0f / fmaxf((float)(end - beg), 1.0f);
    ((float4*)out)[idx] = make_float4(s.x * c, s.y * c, s.z * c, s.w * c);
}

extern "C" void kernel_launch(void* const* d_in, const int* in_sizes, int n_in,
                              void* d_out, int out_size, void* d_ws, size_t ws_size,
                              hipStream_t stream) {
    const float* pos    = (const float*)d_in[0];
    const int*   A      = (const int*)d_in[1];
    const int*   batch  = (const int*)d_in[2];
    const int*   esrc   = (const int*)d_in[3];
    const int*   edst   = (const int*)d_in[4];
    const float* shifts = (const float*)d_in[5];
    const float* cell   = (const float*)d_in[6];
    const float* emb    = (const float*)d_in[7];
    const float* fw1    = (const float*)d_in[8];
    const float* fb1    = (const float*)d_in[9];
    const float* fw2    = (const float*)d_in[10];
    const float* fb2    = (const float*)d_in[11];
    const float* fw3    = (const float*)d_in[12];
    const float* fb3    = (const float*)d_in[13];
    const float* fcw1   = (const float*)d_in[14];
    const float* fcw2   = (const float*)d_in[15];
    const float* fcw3   = (const float*)d_in[16];
    const float* fcw4   = (const float*)d_in[17];
    float* out = (float*)d_out;

    char* ws = (char*)d_ws;
    float* ef      = (float*)(ws + OFF_EF);
    float* T       = (float*)(ws + OFF_T);
    float* g_tT    = (float*)(ws + OFF_G);
    float* sv_table= (float*)(ws + OFF_SV);
    int*   node_off= (int*)(ws + OFF_NOFF);
    int*   cnt_i   = (int*)(ws + OFF_NCNT);
    int*   node_cur= (int*)(ws + OFF_NCUR);
    int*   csr     = (int*)(ws + OFF_CSR);

    hipMemsetAsync(cnt_i, 0, (size_t)2 * N_NODES * 4, stream);

    prep1_kernel<<<P1_GRID, 256, 0, stream>>>(emb, fw1, fb1, fw2, fb2, fw3, fb3,
                                              fcw1, fcw2, fcw3, fcw4, edst,
                                              T, g_tT, cnt_i);
    prep2_kernel<<<P2_GRID, 256, 0, stream>>>(cnt_i, node_off, T, g_tT, sv_table);
    scatter_kernel<<<(N_EDGES + 255) / 256, 256, 0, stream>>>(edst, node_off, node_cur, csr);
    edge_table_kernel<<<N_EDGES / 256, 256, 0, stream>>>(
        pos, batch, esrc, edst, shifts, cell, A, csr, sv_table, ef);
    gather_kernel<<<(N_NODES * 9 + 255) / 256, 256, 0, stream>>>(ef, node_off, out);
}

// Round 12
// 208.012 us; speedup vs baseline: 2.3476x; 1.0374x over previous
//
#include <hip/hip_runtime.h>
#include <math.h>

#define N_NODES 20000
#define N_EDGES 160000

#define NBINS   2048                 // usable bins; bin 2048 = endpoint r=7.5 (sv==0 there exactly)
#define BINS1   2049                 // rows stored per pair
#define RMAX    7.5f

// ws layout (bytes). ~35 MB.
static const size_t OFF_EF  = 0;                                     // ef [E][36] f32 (CSR order)
static const size_t OFF_T   = OFF_EF  + (size_t)N_EDGES * 36 * 4;    // T [100][64][12]
static const size_t OFF_G   = OFF_T   + (size_t)100 * 64 * 12 * 4;   // g_tT [64][2049] (k-major)
static const size_t OFF_SV  = OFF_G   + (size_t)64 * BINS1 * 4;      // sv_table [100][2049][12]
static const size_t OFF_NOFF= OFF_SV  + (size_t)100 * BINS1 * 12 * 4;// node_off [N+1] int
static const size_t OFF_NCNT= OFF_NOFF+ (size_t)(N_NODES + 1) * 4;   // cnt_i [N] int (zeroed)
static const size_t OFF_NCUR= OFF_NCNT+ (size_t)N_NODES * 4;         // node_cur [N] int (zeroed)
static const size_t OFF_CSR = OFF_NCUR+ (size_t)N_NODES * 4;         // csr_edges [E] int

// prep1 grid split: [0,25) ai+T build, [25,58) g-table (64 bins/block), [58,683) histogram
#define P1_T_BLOCKS  25
#define P1_G_BLOCKS  33
#define P1_H_BLOCKS  625
#define P1_GRID (P1_T_BLOCKS + P1_G_BLOCKS + P1_H_BLOCKS)
// prep2 grid: block 0 scan, blocks [1, 1+100*5): sv build (512 bins per block, 2/thread)
#define P2_CHUNKS 5
#define P2_GRID (1 + 100 * P2_CHUNKS)

__device__ __forceinline__ float silu_f(float x) {
    return x / (1.0f + __expf(-x));
}

// ---------------- K1: prep1 — ai+T build | g-table (cooperative) | histogram ---------
__global__ __launch_bounds__(256) void prep1_kernel(
        const float* __restrict__ emb,
        const float* __restrict__ fw1, const float* __restrict__ fb1,
        const float* __restrict__ fw2, const float* __restrict__ fb2,
        const float* __restrict__ fw3, const float* __restrict__ fb3,
        const float* __restrict__ fc_w1, const float* __restrict__ fc_w2,
        const float* __restrict__ fc_w3, const float* __restrict__ fc_w4,
        const int* __restrict__ edst,
        float* __restrict__ T, float* __restrict__ g_tT,
        int* __restrict__ cnt_i) {
    __shared__ float smem[4096];        // T-branch uses 1040; g-branch uses 4096
    int b = blockIdx.x;
    int tid = threadIdx.x;

    if (b < P1_T_BLOCKS) {
        // ---- inline node-type MLP (10 types) then T[pair][k][12] build ----
        float* h1s = smem;              // [10][64]
        float* h2s = smem + 640;        // [10][32]
        float* ai  = smem + 960;        // [10][8]
        for (int idx = tid; idx < 640; idx += 256) {
            int t = idx >> 6, j = idx & 63;
            float acc = fb1[j];
            #pragma unroll
            for (int i = 0; i < 16; i++) acc += emb[t * 16 + i] * fw1[i * 64 + j];
            h1s[idx] = silu_f(acc);
        }
        __syncthreads();
        for (int idx = tid; idx < 320; idx += 256) {
            int t = idx >> 5, j = idx & 31;
            float acc = fb2[j];
            #pragma unroll
            for (int i = 0; i < 64; i++) acc += h1s[t * 64 + i] * fw2[i * 32 + j];
            h2s[idx] = silu_f(acc);
        }
        __syncthreads();
        if (tid < 80) {
            int t = tid >> 3, j = tid & 7;
            float acc = fb3[j];
            #pragma unroll
            for (int i = 0; i < 32; i++) acc += h2s[t * 32 + i] * fw3[i * 8 + j];
            ai[tid] = acc;
        }
        __syncthreads();

        int idx = b * 256 + tid;        // 6400 = 100 pairs x 64 k
        int pair = idx >> 6;
        int k = idx & 63;
        int ts = pair / 10, td = pair - ts * 10;
        float a[8], bb[8];
        #pragma unroll
        for (int i = 0; i < 8; i++) a[i] = ai[ts * 8 + i];
        #pragma unroll
        for (int i = 0; i < 8; i++) bb[i] = ai[td * 8 + i];
        float sv[12];
        #pragma unroll
        for (int i = 0; i < 12; i++) sv[i] = 0.0f;
        const float* wk = fc_w4 + k * 768;
        #pragma unroll 2
        for (int u = 0; u < 8; u++) {
            #pragma unroll
            for (int v = 0; v < 8; v++) {
                float ab = a[u] * bb[v];
                const float* wp = wk + u * 32 + v * 4;
                float4 w0 = *(const float4*)(wp);
                float4 w1 = *(const float4*)(wp + 256);
                float4 w2 = *(const float4*)(wp + 512);
                sv[0] += ab * w0.x; sv[1] += ab * w0.y; sv[2]  += ab * w0.z; sv[3]  += ab * w0.w;
                sv[4] += ab * w1.x; sv[5] += ab * w1.y; sv[6]  += ab * w1.z; sv[7]  += ab * w1.w;
                sv[8] += ab * w2.x; sv[9] += ab * w2.y; sv[10] += ab * w2.z; sv[11] += ab * w2.w;
            }
        }
        float* tp = T + pair * 768 + k * 12;
        #pragma unroll
        for (int j = 0; j < 12; j++) tp[j] = sv[j];
    } else if (b < P1_T_BLOCKS + P1_G_BLOCKS) {
        // ---- g-table, cooperative: 64 bins/block (lane=bin), wave owns 16 channels ----
        int lane = tid & 63;
        int wq = __builtin_amdgcn_readfirstlane(tid >> 6);
        int bin = (b - P1_T_BLOCKS) * 64 + lane;
        bool valid = (bin <= NBINS);
        float r = (float)bin * (RMAX / (float)NBINS);

        float rb[16];
        const float step = 5.0f / 17.0f;
        const float istep = 17.0f / 5.0f;
        const float rsc = 4.0f / 1.12f;
        #pragma unroll
        for (int i = 0; i < 16; i++) {
            float dd = (r - (float)(i + 1) * step) * istep;
            rb[i] = __expf(-dd * dd) * rsc;
        }

        // L1: 16 -> 64 (weight addresses wave-uniform -> scalar loads)
        #pragma unroll
        for (int jj = 0; jj < 16; jj++) {
            int j = wq * 16 + jj;
            float a0 = 0, a1 = 0, a2 = 0, a3 = 0;
            #pragma unroll
            for (int i = 0; i < 16; i += 4) {
                a0 += rb[i]     * fc_w1[(i)     * 64 + j];
                a1 += rb[i + 1] * fc_w1[(i + 1) * 64 + j];
                a2 += rb[i + 2] * fc_w1[(i + 2) * 64 + j];
                a3 += rb[i + 3] * fc_w1[(i + 3) * 64 + j];
            }
            smem[j * 64 + lane] = silu_f(((a0 + a1) + (a2 + a3)) * 0.25f);
        }
        __syncthreads();

        // L2: 64 -> 64
        float acc[16];
        #pragma unroll
        for (int jj = 0; jj < 16; jj++) acc[jj] = 0.0f;
        #pragma unroll
        for (int c = 0; c < 4; c++) {
            float hc[16];
            #pragma unroll
            for (int i = 0; i < 16; i++) hc[i] = smem[(c * 16 + i) * 64 + lane];
            #pragma unroll
            for (int jj = 0; jj < 16; jj++) {
                int j = wq * 16 + jj;
                #pragma unroll
                for (int i = 0; i < 16; i++) acc[jj] += hc[i] * fc_w2[(c * 16 + i) * 64 + j];
            }
        }
        __syncthreads();
        #pragma unroll
        for (int jj = 0; jj < 16; jj++) smem[(wq * 16 + jj) * 64 + lane] = silu_f(acc[jj] * 0.125f);
        __syncthreads();

        // L3: 64 -> 64 -> g_tT[k][bin] (lane-coalesced stores)
        #pragma unroll
        for (int jj = 0; jj < 16; jj++) acc[jj] = 0.0f;
        #pragma unroll
        for (int c = 0; c < 4; c++) {
            float hc[16];
            #pragma unroll
            for (int i = 0; i < 16; i++) hc[i] = smem[(c * 16 + i) * 64 + lane];
            #pragma unroll
            for (int jj = 0; jj < 16; jj++) {
                int j = wq * 16 + jj;
                #pragma unroll
                for (int i = 0; i < 16; i++) acc[jj] += hc[i] * fc_w3[(c * 16 + i) * 64 + j];
            }
        }
        if (valid) {
            #pragma unroll
            for (int jj = 0; jj < 16; jj++)
                g_tT[(size_t)(wq * 16 + jj) * BINS1 + bin] = silu_f(acc[jj] * 0.125f);
        }
    } else {
        // ---- histogram of edge_dst ----
        int e = (b - P1_T_BLOCKS - P1_G_BLOCKS) * 256 + tid;
        if (e < N_EDGES) atomicAdd(&cnt_i[edst[e]], 1);
    }
}

// ---------------- K2: prep2 — scan (block 0) | sv_table = (1/64) g @ T ---------------
// sv blocks: pair from blockIdx; each block covers 512 bins, 2 per thread (dual g streams).
__global__ __launch_bounds__(256) void prep2_kernel(
        const int* __restrict__ cnt_i, int* __restrict__ node_off,
        const float* __restrict__ T, const float* __restrict__ g_tT,
        float* __restrict__ sv_table) {
    __shared__ int part[256];
    int b = blockIdx.x;
    int tid = threadIdx.x;

    if (b == 0) {
        int base = tid * 79;            // 256 * 79 >= 20000
        int s = 0;
        for (int i = 0; i < 79; i++) {
            int n = base + i;
            if (n < N_NODES) s += cnt_i[n];
        }
        part[tid] = s;
        __syncthreads();
        for (int off = 1; off < 256; off <<= 1) {
            int v = part[tid];
            int add = (tid >= off) ? part[tid - off] : 0;
            __syncthreads();
            part[tid] = v + add;
            __syncthreads();
        }
        int run = (tid == 0) ? 0 : part[tid - 1];
        for (int i = 0; i < 79; i++) {
            int n = base + i;
            if (n < N_NODES) { node_off[n] = run; run += cnt_i[n]; }
        }
        if (tid == 255) node_off[N_NODES] = part[255];
        return;
    }

    int idx = b - 1;
    int pair = idx / P2_CHUNKS;
    int chunk = idx - pair * P2_CHUNKS;
    int b0 = chunk * 512 + tid;
    int b1 = b0 + 256;
    bool v0 = (b0 <= NBINS), v1 = (b1 <= NBINS);
    int rb0 = v0 ? b0 : NBINS;          // clamp to stay in-bounds
    int rb1 = v1 ? b1 : NBINS;

    float acc0[12], acc1[12];
    #pragma unroll
    for (int j = 0; j < 12; j++) { acc0[j] = 0.0f; acc1[j] = 0.0f; }
    const float* Tp = T + pair * 768;
    #pragma unroll 4
    for (int k = 0; k < 64; k++) {
        float g0 = g_tT[(size_t)k * BINS1 + rb0];  // two independent coalesced streams
        float g1 = g_tT[(size_t)k * BINS1 + rb1];
        const float* tr = Tp + k * 12;             // pair uniform per block -> s_load
        float4 t0 = *(const float4*)(tr);
        float4 t1 = *(const float4*)(tr + 4);
        float4 t2 = *(const float4*)(tr + 8);
        acc0[0] += g0 * t0.x; acc0[1] += g0 * t0.y; acc0[2]  += g0 * t0.z; acc0[3]  += g0 * t0.w;
        acc0[4] += g0 * t1.x; acc0[5] += g0 * t1.y; acc0[6]  += g0 * t1.z; acc0[7]  += g0 * t1.w;
        acc0[8] += g0 * t2.x; acc0[9] += g0 * t2.y; acc0[10] += g0 * t2.z; acc0[11] += g0 * t2.w;
        acc1[0] += g1 * t0.x; acc1[1] += g1 * t0.y; acc1[2]  += g1 * t0.z; acc1[3]  += g1 * t0.w;
        acc1[4] += g1 * t1.x; acc1[5] += g1 * t1.y; acc1[6]  += g1 * t1.z; acc1[7]  += g1 * t1.w;
        acc1[8] += g1 * t2.x; acc1[9] += g1 * t2.y; acc1[10] += g1 * t2.z; acc1[11] += g1 * t2.w;
    }
    const float isc = 1.0f / 64.0f;
    if (v0) {
        float* o = sv_table + ((size_t)pair * BINS1 + b0) * 12;
        #pragma unroll
        for (int j = 0; j < 12; j++) o[j] = acc0[j] * isc;
    }
    if (v1) {
        float* o = sv_table + ((size_t)pair * BINS1 + b1) * 12;
        #pragma unroll
        for (int j = 0; j < 12; j++) o[j] = acc1[j] * isc;
    }
}

// ---------------- K3: scatter edge ids into CSR --------------------------------------
__global__ void scatter_kernel(const int* __restrict__ edst,
                               const int* __restrict__ node_off,
                               int* __restrict__ node_cur,
                               int* __restrict__ csr_edges) {
    int e = blockIdx.x * 256 + threadIdx.x;
    if (e >= N_EDGES) return;
    int d = edst[e];
    int slot = atomicAdd(&node_cur[d], 1);
    csr_edges[node_off[d] + slot] = e;
}

// ---------------- K4: edge kernel — geometry + table lerp + sh epilogue --------------
__global__ __launch_bounds__(256) void edge_table_kernel(
        const float* __restrict__ pos, const int* __restrict__ batch,
        const int* __restrict__ esrc, const int* __restrict__ edst,
        const float* __restrict__ shifts, const float* __restrict__ cell,
        const int* __restrict__ A, const int* __restrict__ csr_edges,
        const float* __restrict__ sv_table, float* __restrict__ ef) {
    int p = blockIdx.x * 256 + threadIdx.x;    // grid exact: 625*256
    int e = csr_edges[p];

    int s = esrc[e], d = edst[e];
    int gb = batch[s];
    float t0 = shifts[e * 3 + 0], t1 = shifts[e * 3 + 1], t2 = shifts[e * 3 + 2];
    const float* C = cell + gb * 9;
    float shx = t0 * C[0] + t1 * C[3] + t2 * C[6];
    float shy = t0 * C[1] + t1 * C[4] + t2 * C[7];
    float shz = t0 * C[2] + t1 * C[5] + t2 * C[8];
    float ex = pos[d * 3 + 0] - pos[s * 3 + 0] + shx;
    float ey = pos[d * 3 + 1] - pos[s * 3 + 1] + shy;
    float ez = pos[d * 3 + 2] - pos[s * 3 + 2] + shz;
    float r = sqrtf(ex * ex + ey * ey + ez * ez);
    float inv = 1.0f / fmaxf(r, 1e-9f);
    float x = ex * inv, y = ey * inv, z = ez * inv;

    float sv[12];
    if (r >= RMAX) {
        #pragma unroll
        for (int j = 0; j < 12; j++) sv[j] = 0.0f;
    } else {
        int pair = A[s] * 10 + A[d];
        float t = r * ((float)NBINS / RMAX);
        int i = (int)t;
        i = (i > NBINS - 1) ? (NBINS - 1) : i;
        float f = t - (float)i;
        const float* r0 = sv_table + ((size_t)pair * BINS1 + i) * 12;  // rows i,i+1 contiguous (96B)
        #pragma unroll
        for (int j = 0; j < 12; j++) {
            float lo = r0[j], hi = r0[12 + j];
            sv[j] = lo + f * (hi - lo);
        }
    }

    const float S3  = 1.7320508075688772f;
    const float S15 = 3.8729833462074170f;
    const float S5  = 2.2360679774997896f;
    float sh1v[3] = { S3 * y, S3 * z, S3 * x };
    float sh2v[5] = { S15 * x * y, S15 * y * z, 0.5f * S5 * (3.0f * z * z - 1.0f),
                      S15 * x * z, 0.5f * S15 * (x * x - y * y) };

    float o[36];
    #pragma unroll
    for (int w = 0; w < 4; w++) o[w] = sv[w];
    #pragma unroll
    for (int w = 0; w < 4; w++) {
        float sw = sv[4 + w];
        #pragma unroll
        for (int j = 0; j < 3; j++) o[4 + w * 3 + j] = sw * sh1v[j];
    }
    #pragma unroll
    for (int w = 0; w < 4; w++) {
        float sw = sv[8 + w];
        #pragma unroll
        for (int j = 0; j < 5; j++) o[16 + w * 5 + j] = sw * sh2v[j];
    }
    float4* dst = (float4*)(ef + (size_t)p * 36);   // 144B = 9 x float4, aligned
    #pragma unroll
    for (int q = 0; q < 9; q++) dst[q] = ((float4*)o)[q];
}

// ---------------- K5: gather + mean (float4 stream per node) -------------------------
__global__ void gather_kernel(const float* __restrict__ ef,
                              const int* __restrict__ node_off,
                              float* __restrict__ out) {
    int idx = blockIdx.x * 256 + threadIdx.x;   // (node, float4-group)
    if (idx >= N_NODES * 9) return;
    int n = idx / 9;
    int g = idx - n * 9;
    int beg = node_off[n], end = node_off[n + 1];
    const float4* ef4 = (const float4*)ef;
    float4 s = make_float4(0.f, 0.f, 0.f, 0.f);
    for (int p = beg; p < end; p++) {
        float4 v = ef4[(size_t)p * 9 + g];
        s.x += v.x; s.y += v.y; s.z += v.z; s.w += v.w;
    }
    float c = 1.0f / fmaxf((float)(end - beg), 1.0f);
    ((float4*)out)[idx] = make_float4(s.x * c, s.y * c, s.z * c, s.w * c);
}

extern "C" void kernel_launch(void* const* d_in, const int* in_sizes, int n_in,
                              void* d_out, int out_size, void* d_ws, size_t ws_size,
                              hipStream_t stream) {
    const float* pos    = (const float*)d_in[0];
    const int*   A      = (const int*)d_in[1];
    const int*   batch  = (const int*)d_in[2];
    const int*   esrc   = (const int*)d_in[3];
    const int*   edst   = (const int*)d_in[4];
    const float* shifts = (const float*)d_in[5];
    const float* cell   = (const float*)d_in[6];
    const float* emb    = (const float*)d_in[7];
    const float* fw1    = (const float*)d_in[8];
    const float* fb1    = (const float*)d_in[9];
    const float* fw2    = (const float*)d_in[10];
    const float* fb2    = (const float*)d_in[11];
    const float* fw3    = (const float*)d_in[12];
    const float* fb3    = (const float*)d_in[13];
    const float* fcw1   = (const float*)d_in[14];
    const float* fcw2   = (const float*)d_in[15];
    const float* fcw3   = (const float*)d_in[16];
    const float* fcw4   = (const float*)d_in[17];
    float* out = (float*)d_out;

    char* ws = (char*)d_ws;
    float* ef      = (float*)(ws + OFF_EF);
    float* T       = (float*)(ws + OFF_T);
    float* g_tT    = (float*)(ws + OFF_G);
    float* sv_table= (float*)(ws + OFF_SV);
    int*   node_off= (int*)(ws + OFF_NOFF);
    int*   cnt_i   = (int*)(ws + OFF_NCNT);
    int*   node_cur= (int*)(ws + OFF_NCUR);
    int*   csr     = (int*)(ws + OFF_CSR);

    hipMemsetAsync(cnt_i, 0, (size_t)2 * N_NODES * 4, stream);

    prep1_kernel<<<P1_GRID, 256, 0, stream>>>(emb, fw1, fb1, fw2, fb2, fw3, fb3,
                                              fcw1, fcw2, fcw3, fcw4, edst,
                                              T, g_tT, cnt_i);
    prep2_kernel<<<P2_GRID, 256, 0, stream>>>(cnt_i, node_off, T, g_tT, sv_table);
    scatter_kernel<<<(N_EDGES + 255) / 256, 256, 0, stream>>>(edst, node_off, node_cur, csr);
    edge_table_kernel<<<N_EDGES / 256, 256, 0, stream>>>(
        pos, batch, esrc, edst, shifts, cell, A, csr, sv_table, ef);
    gather_kernel<<<(N_NODES * 9 + 255) / 256, 256, 0, stream>>>(ef, node_off, out);
}

// Round 13
// 202.363 us; speedup vs baseline: 2.4131x; 1.0279x over previous
//
#include <hip/hip_runtime.h>
#include <math.h>

#define N_NODES 20000
#define N_EDGES 160000

#define NBINS   1024                 // usable bins; bin 1024 = endpoint r=7.5 (sv==0 there exactly)
#define BINS1   1025                 // rows stored per pair
#define RMAX    7.5f

// ws layout (bytes). ~30 MB.
static const size_t OFF_EF  = 0;                                     // ef [E][36] f32 (node-grouped rows)
static const size_t OFF_T   = OFF_EF  + (size_t)N_EDGES * 36 * 4;    // T [100][64][12]
static const size_t OFF_G   = OFF_T   + (size_t)100 * 64 * 12 * 4;   // g_tT [64][1025] (k-major)
static const size_t OFF_SV  = OFF_G   + (size_t)64 * BINS1 * 4;      // sv_table [100][1025][12]
static const size_t OFF_NOFF= OFF_SV  + (size_t)100 * BINS1 * 12 * 4;// node_off [N+1] int
static const size_t OFF_NCNT= OFF_NOFF+ (size_t)(N_NODES + 1) * 4;   // cnt_i [N] int (zeroed)
static const size_t OFF_NCUR= OFF_NCNT+ (size_t)N_NODES * 4;         // node_cur [N] int (zeroed)

// prep1 grid split: [0,25) ai+T build, [25,42) g-table (64 bins/block), [42,667) histogram
#define P1_T_BLOCKS  25
#define P1_G_BLOCKS  17
#define P1_H_BLOCKS  625
#define P1_GRID (P1_T_BLOCKS + P1_G_BLOCKS + P1_H_BLOCKS)
// prep2 grid: block 0 scan, blocks [1, 1+100*3): sv build (512 bins per block, 2/thread)
#define P2_CHUNKS 3
#define P2_GRID (1 + 100 * P2_CHUNKS)

__device__ __forceinline__ float silu_f(float x) {
    return x / (1.0f + __expf(-x));
}

// ---------------- K1: prep1 — ai+T build | g-table (cooperative) | histogram ---------
__global__ __launch_bounds__(256) void prep1_kernel(
        const float* __restrict__ emb,
        const float* __restrict__ fw1, const float* __restrict__ fb1,
        const float* __restrict__ fw2, const float* __restrict__ fb2,
        const float* __restrict__ fw3, const float* __restrict__ fb3,
        const float* __restrict__ fc_w1, const float* __restrict__ fc_w2,
        const float* __restrict__ fc_w3, const float* __restrict__ fc_w4,
        const int* __restrict__ edst,
        float* __restrict__ T, float* __restrict__ g_tT,
        int* __restrict__ cnt_i) {
    __shared__ float smem[4096];        // T-branch uses 1040; g-branch uses 4096
    int b = blockIdx.x;
    int tid = threadIdx.x;

    if (b < P1_T_BLOCKS) {
        // ---- inline node-type MLP (10 types) then T[pair][k][12] build ----
        float* h1s = smem;              // [10][64]
        float* h2s = smem + 640;        // [10][32]
        float* ai  = smem + 960;        // [10][8]
        for (int idx = tid; idx < 640; idx += 256) {
            int t = idx >> 6, j = idx & 63;
            float acc = fb1[j];
            #pragma unroll
            for (int i = 0; i < 16; i++) acc += emb[t * 16 + i] * fw1[i * 64 + j];
            h1s[idx] = silu_f(acc);
        }
        __syncthreads();
        for (int idx = tid; idx < 320; idx += 256) {
            int t = idx >> 5, j = idx & 31;
            float acc = fb2[j];
            #pragma unroll
            for (int i = 0; i < 64; i++) acc += h1s[t * 64 + i] * fw2[i * 32 + j];
            h2s[idx] = silu_f(acc);
        }
        __syncthreads();
        if (tid < 80) {
            int t = tid >> 3, j = tid & 7;
            float acc = fb3[j];
            #pragma unroll
            for (int i = 0; i < 32; i++) acc += h2s[t * 32 + i] * fw3[i * 8 + j];
            ai[tid] = acc;
        }
        __syncthreads();

        int idx = b * 256 + tid;        // 6400 = 100 pairs x 64 k
        int pair = idx >> 6;
        int k = idx & 63;
        int ts = pair / 10, td = pair - ts * 10;
        float a[8], bb[8];
        #pragma unroll
        for (int i = 0; i < 8; i++) a[i] = ai[ts * 8 + i];
        #pragma unroll
        for (int i = 0; i < 8; i++) bb[i] = ai[td * 8 + i];
        float sv[12];
        #pragma unroll
        for (int i = 0; i < 12; i++) sv[i] = 0.0f;
        const float* wk = fc_w4 + k * 768;
        #pragma unroll 2
        for (int u = 0; u < 8; u++) {
            #pragma unroll
            for (int v = 0; v < 8; v++) {
                float ab = a[u] * bb[v];
                const float* wp = wk + u * 32 + v * 4;
                float4 w0 = *(const float4*)(wp);
                float4 w1 = *(const float4*)(wp + 256);
                float4 w2 = *(const float4*)(wp + 512);
                sv[0] += ab * w0.x; sv[1] += ab * w0.y; sv[2]  += ab * w0.z; sv[3]  += ab * w0.w;
                sv[4] += ab * w1.x; sv[5] += ab * w1.y; sv[6]  += ab * w1.z; sv[7]  += ab * w1.w;
                sv[8] += ab * w2.x; sv[9] += ab * w2.y; sv[10] += ab * w2.z; sv[11] += ab * w2.w;
            }
        }
        float* tp = T + pair * 768 + k * 12;
        #pragma unroll
        for (int j = 0; j < 12; j++) tp[j] = sv[j];
    } else if (b < P1_T_BLOCKS + P1_G_BLOCKS) {
        // ---- g-table, cooperative: 64 bins/block (lane=bin), wave owns 16 channels ----
        int lane = tid & 63;
        int wq = __builtin_amdgcn_readfirstlane(tid >> 6);
        int bin = (b - P1_T_BLOCKS) * 64 + lane;
        bool valid = (bin <= NBINS);
        float r = (float)bin * (RMAX / (float)NBINS);

        float rb[16];
        const float step = 5.0f / 17.0f;
        const float istep = 17.0f / 5.0f;
        const float rsc = 4.0f / 1.12f;
        #pragma unroll
        for (int i = 0; i < 16; i++) {
            float dd = (r - (float)(i + 1) * step) * istep;
            rb[i] = __expf(-dd * dd) * rsc;
        }

        // L1: 16 -> 64 (weight addresses wave-uniform -> scalar loads)
        #pragma unroll
        for (int jj = 0; jj < 16; jj++) {
            int j = wq * 16 + jj;
            float a0 = 0, a1 = 0, a2 = 0, a3 = 0;
            #pragma unroll
            for (int i = 0; i < 16; i += 4) {
                a0 += rb[i]     * fc_w1[(i)     * 64 + j];
                a1 += rb[i + 1] * fc_w1[(i + 1) * 64 + j];
                a2 += rb[i + 2] * fc_w1[(i + 2) * 64 + j];
                a3 += rb[i + 3] * fc_w1[(i + 3) * 64 + j];
            }
            smem[j * 64 + lane] = silu_f(((a0 + a1) + (a2 + a3)) * 0.25f);
        }
        __syncthreads();

        // L2: 64 -> 64
        float acc[16];
        #pragma unroll
        for (int jj = 0; jj < 16; jj++) acc[jj] = 0.0f;
        #pragma unroll
        for (int c = 0; c < 4; c++) {
            float hc[16];
            #pragma unroll
            for (int i = 0; i < 16; i++) hc[i] = smem[(c * 16 + i) * 64 + lane];
            #pragma unroll
            for (int jj = 0; jj < 16; jj++) {
                int j = wq * 16 + jj;
                #pragma unroll
                for (int i = 0; i < 16; i++) acc[jj] += hc[i] * fc_w2[(c * 16 + i) * 64 + j];
            }
        }
        __syncthreads();
        #pragma unroll
        for (int jj = 0; jj < 16; jj++) smem[(wq * 16 + jj) * 64 + lane] = silu_f(acc[jj] * 0.125f);
        __syncthreads();

        // L3: 64 -> 64 -> g_tT[k][bin] (lane-coalesced stores)
        #pragma unroll
        for (int jj = 0; jj < 16; jj++) acc[jj] = 0.0f;
        #pragma unroll
        for (int c = 0; c < 4; c++) {
            float hc[16];
            #pragma unroll
            for (int i = 0; i < 16; i++) hc[i] = smem[(c * 16 + i) * 64 + lane];
            #pragma unroll
            for (int jj = 0; jj < 16; jj++) {
                int j = wq * 16 + jj;
                #pragma unroll
                for (int i = 0; i < 16; i++) acc[jj] += hc[i] * fc_w3[(c * 16 + i) * 64 + j];
            }
        }
        if (valid) {
            #pragma unroll
            for (int jj = 0; jj < 16; jj++)
                g_tT[(size_t)(wq * 16 + jj) * BINS1 + bin] = silu_f(acc[jj] * 0.125f);
        }
    } else {
        // ---- histogram of edge_dst ----
        int e = (b - P1_T_BLOCKS - P1_G_BLOCKS) * 256 + tid;
        if (e < N_EDGES) atomicAdd(&cnt_i[edst[e]], 1);
    }
}

// ---------------- K2: prep2 — scan (block 0) | sv_table = (1/64) g @ T ---------------
__global__ __launch_bounds__(256) void prep2_kernel(
        const int* __restrict__ cnt_i, int* __restrict__ node_off,
        const float* __restrict__ T, const float* __restrict__ g_tT,
        float* __restrict__ sv_table) {
    __shared__ int part[256];
    int b = blockIdx.x;
    int tid = threadIdx.x;

    if (b == 0) {
        int base = tid * 79;            // 256 * 79 >= 20000
        int s = 0;
        for (int i = 0; i < 79; i++) {
            int n = base + i;
            if (n < N_NODES) s += cnt_i[n];
        }
        part[tid] = s;
        __syncthreads();
        for (int off = 1; off < 256; off <<= 1) {
            int v = part[tid];
            int add = (tid >= off) ? part[tid - off] : 0;
            __syncthreads();
            part[tid] = v + add;
            __syncthreads();
        }
        int run = (tid == 0) ? 0 : part[tid - 1];
        for (int i = 0; i < 79; i++) {
            int n = base + i;
            if (n < N_NODES) { node_off[n] = run; run += cnt_i[n]; }
        }
        if (tid == 255) node_off[N_NODES] = part[255];
        return;
    }

    int idx = b - 1;
    int pair = idx / P2_CHUNKS;
    int chunk = idx - pair * P2_CHUNKS;
    int b0 = chunk * 512 + tid;
    int b1 = b0 + 256;
    bool v0 = (b0 <= NBINS), v1 = (b1 <= NBINS);
    int rb0 = v0 ? b0 : NBINS;          // clamp to stay in-bounds
    int rb1 = v1 ? b1 : NBINS;

    float acc0[12], acc1[12];
    #pragma unroll
    for (int j = 0; j < 12; j++) { acc0[j] = 0.0f; acc1[j] = 0.0f; }
    const float* Tp = T + pair * 768;
    #pragma unroll 4
    for (int k = 0; k < 64; k++) {
        float g0 = g_tT[(size_t)k * BINS1 + rb0];  // two independent coalesced streams
        float g1 = g_tT[(size_t)k * BINS1 + rb1];
        const float* tr = Tp + k * 12;             // pair uniform per block -> s_load
        float4 t0 = *(const float4*)(tr);
        float4 t1 = *(const float4*)(tr + 4);
        float4 t2 = *(const float4*)(tr + 8);
        acc0[0] += g0 * t0.x; acc0[1] += g0 * t0.y; acc0[2]  += g0 * t0.z; acc0[3]  += g0 * t0.w;
        acc0[4] += g0 * t1.x; acc0[5] += g0 * t1.y; acc0[6]  += g0 * t1.z; acc0[7]  += g0 * t1.w;
        acc0[8] += g0 * t2.x; acc0[9] += g0 * t2.y; acc0[10] += g0 * t2.z; acc0[11] += g0 * t2.w;
        acc1[0] += g1 * t0.x; acc1[1] += g1 * t0.y; acc1[2]  += g1 * t0.z; acc1[3]  += g1 * t0.w;
        acc1[4] += g1 * t1.x; acc1[5] += g1 * t1.y; acc1[6]  += g1 * t1.z; acc1[7]  += g1 * t1.w;
        acc1[8] += g1 * t2.x; acc1[9] += g1 * t2.y; acc1[10] += g1 * t2.z; acc1[11] += g1 * t2.w;
    }
    const float isc = 1.0f / 64.0f;
    if (v0) {
        float* o = sv_table + ((size_t)pair * BINS1 + b0) * 12;
        #pragma unroll
        for (int j = 0; j < 12; j++) o[j] = acc0[j] * isc;
    }
    if (v1) {
        float* o = sv_table + ((size_t)pair * BINS1 + b1) * 12;
        #pragma unroll
        for (int j = 0; j < 12; j++) o[j] = acc1[j] * isc;
    }
}

// ---------------- K3: edge kernel — coalesced inputs, self-assigned CSR slot ---------
__global__ __launch_bounds__(256) void edge_table_kernel(
        const float* __restrict__ pos, const int* __restrict__ batch,
        const int* __restrict__ esrc, const int* __restrict__ edst,
        const float* __restrict__ shifts, const float* __restrict__ cell,
        const int* __restrict__ A,
        const int* __restrict__ node_off, int* __restrict__ node_cur,
        const float* __restrict__ sv_table, float* __restrict__ ef) {
    int e = blockIdx.x * 256 + threadIdx.x;    // grid exact: 625*256; all input reads coalesced
    int s = esrc[e], d = edst[e];
    int gb = batch[s];
    float t0 = shifts[e * 3 + 0], t1 = shifts[e * 3 + 1], t2 = shifts[e * 3 + 2];
    const float* C = cell + gb * 9;
    float shx = t0 * C[0] + t1 * C[3] + t2 * C[6];
    float shy = t0 * C[1] + t1 * C[4] + t2 * C[7];
    float shz = t0 * C[2] + t1 * C[5] + t2 * C[8];
    float ex = pos[d * 3 + 0] - pos[s * 3 + 0] + shx;
    float ey = pos[d * 3 + 1] - pos[s * 3 + 1] + shy;
    float ez = pos[d * 3 + 2] - pos[s * 3 + 2] + shz;
    float r = sqrtf(ex * ex + ey * ey + ez * ez);
    float inv = 1.0f / fmaxf(r, 1e-9f);
    float x = ex * inv, y = ey * inv, z = ez * inv;

    float sv[12];
    if (r >= RMAX) {
        #pragma unroll
        for (int j = 0; j < 12; j++) sv[j] = 0.0f;
    } else {
        int pair = A[s] * 10 + A[d];
        float t = r * ((float)NBINS / RMAX);
        int i = (int)t;
        i = (i > NBINS - 1) ? (NBINS - 1) : i;
        float f = t - (float)i;
        const float* r0 = sv_table + ((size_t)pair * BINS1 + i) * 12;  // rows i,i+1 contiguous (96B, L2)
        #pragma unroll
        for (int j = 0; j < 12; j++) {
            float lo = r0[j], hi = r0[12 + j];
            sv[j] = lo + f * (hi - lo);
        }
    }

    const float S3  = 1.7320508075688772f;
    const float S15 = 3.8729833462074170f;
    const float S5  = 2.2360679774997896f;
    float sh1v[3] = { S3 * y, S3 * z, S3 * x };
    float sh2v[5] = { S15 * x * y, S15 * y * z, 0.5f * S5 * (3.0f * z * z - 1.0f),
                      S15 * x * z, 0.5f * S15 * (x * x - y * y) };

    float o[36];
    #pragma unroll
    for (int w = 0; w < 4; w++) o[w] = sv[w];
    #pragma unroll
    for (int w = 0; w < 4; w++) {
        float sw = sv[4 + w];
        #pragma unroll
        for (int j = 0; j < 3; j++) o[4 + w * 3 + j] = sw * sh1v[j];
    }
    #pragma unroll
    for (int w = 0; w < 4; w++) {
        float sw = sv[8 + w];
        #pragma unroll
        for (int j = 0; j < 5; j++) o[16 + w * 5 + j] = sw * sh2v[j];
    }

    // self-assigned slot within the node's CSR segment: ef stays node-grouped, so the
    // gather still streams contiguously. No csr array, no scatter dispatch.
    int slot = atomicAdd(&node_cur[d], 1);
    int p = node_off[d] + slot;
    float4* dst = (float4*)(ef + (size_t)p * 36);   // 144B = 9 x float4, aligned
    #pragma unroll
    for (int q = 0; q < 9; q++) dst[q] = ((float4*)o)[q];
}

// ---------------- K4: gather + mean (float4 stream per node) -------------------------
__global__ void gather_kernel(const float* __restrict__ ef,
                              const int* __restrict__ node_off,
                              float* __restrict__ out) {
    int idx = blockIdx.x * 256 + threadIdx.x;   // (node, float4-group)
    if (idx >= N_NODES * 9) return;
    int n = idx / 9;
    int g = idx - n * 9;
    int beg = node_off[n], end = node_off[n + 1];
    const float4* ef4 = (const float4*)ef;
    float4 s = make_float4(0.f, 0.f, 0.f, 0.f);
    for (int p = beg; p < end; p++) {
        float4 v = ef4[(size_t)p * 9 + g];
        s.x += v.x; s.y += v.y; s.z += v.z; s.w += v.w;
    }
    float c = 1.0f / fmaxf((float)(end - beg), 1.0f);
    ((float4*)out)[idx] = make_float4(s.x * c, s.y * c, s.z * c, s.w * c);
}

extern "C" void kernel_launch(void* const* d_in, const int* in_sizes, int n_in,
                              void* d_out, int out_size, void* d_ws, size_t ws_size,
                              hipStream_t stream) {
    const float* pos    = (const float*)d_in[0];
    const int*   A      = (const int*)d_in[1];
    const int*   batch  = (const int*)d_in[2];
    const int*   esrc   = (const int*)d_in[3];
    const int*   edst   = (const int*)d_in[4];
    const float* shifts = (const float*)d_in[5];
    const float* cell   = (const float*)d_in[6];
    const float* emb    = (const float*)d_in[7];
    const float* fw1    = (const float*)d_in[8];
    const float* fb1    = (const float*)d_in[9];
    const float* fw2    = (const float*)d_in[10];
    const float* fb2    = (const float*)d_in[11];
    const float* fw3    = (const float*)d_in[12];
    const float* fb3    = (const float*)d_in[13];
    const float* fcw1   = (const float*)d_in[14];
    const float* fcw2   = (const float*)d_in[15];
    const float* fcw3   = (const float*)d_in[16];
    const float* fcw4   = (const float*)d_in[17];
    float* out = (float*)d_out;

    char* ws = (char*)d_ws;
    float* ef      = (float*)(ws + OFF_EF);
    float* T       = (float*)(ws + OFF_T);
    float* g_tT    = (float*)(ws + OFF_G);
    float* sv_table= (float*)(ws + OFF_SV);
    int*   node_off= (int*)(ws + OFF_NOFF);
    int*   cnt_i   = (int*)(ws + OFF_NCNT);
    int*   node_cur= (int*)(ws + OFF_NCUR);

    hipMemsetAsync(cnt_i, 0, (size_t)2 * N_NODES * 4, stream);

    prep1_kernel<<<P1_GRID, 256, 0, stream>>>(emb, fw1, fb1, fw2, fb2, fw3, fb3,
                                              fcw1, fcw2, fcw3, fcw4, edst,
                                              T, g_tT, cnt_i);
    prep2_kernel<<<P2_GRID, 256, 0, stream>>>(cnt_i, node_off, T, g_tT, sv_table);
    edge_table_kernel<<<N_EDGES / 256, 256, 0, stream>>>(
        pos, batch, esrc, edst, shifts, cell, A, node_off, node_cur, sv_table, ef);
    gather_kernel<<<(N_NODES * 9 + 255) / 256, 256, 0, stream>>>(ef, node_off, out);
}

// Round 14
// 201.154 us; speedup vs baseline: 2.4276x; 1.0060x over previous
//
#include <hip/hip_runtime.h>
#include <math.h>

#define N_NODES 20000
#define N_EDGES 160000
#define EHALF   80000

#define NBINS   512                  // usable bins; bin 512 = endpoint r=7.5 (sv==0 there exactly)
#define BINS1   513                  // rows stored per pair
#define RMAX    7.5f

// ws layout (bytes). ~28 MB.
static const size_t OFF_EF  = 0;                                     // ef [E][36] f32 (node-grouped rows)
static const size_t OFF_T   = OFF_EF  + (size_t)N_EDGES * 36 * 4;    // T [100][64][12]
static const size_t OFF_G   = OFF_T   + (size_t)100 * 64 * 12 * 4;   // g_tT [64][513] (k-major)
static const size_t OFF_SV  = OFF_G   + (size_t)64 * BINS1 * 4;      // sv_table [100][513][12]
static const size_t OFF_NOFF= OFF_SV  + (size_t)100 * BINS1 * 12 * 4;// node_off [N+1] int
static const size_t OFF_NCNT= OFF_NOFF+ (size_t)(N_NODES + 1) * 4;   // cnt_i [N] int (zeroed)
static const size_t OFF_NCUR= OFF_NCNT+ (size_t)N_NODES * 4;         // node_cur [N] int (zeroed)

// prep1 grid split: [0,25) ai+T build, [25,34) g-table (64 bins/block), [34,659) histogram
#define P1_T_BLOCKS  25
#define P1_G_BLOCKS  9
#define P1_H_BLOCKS  625
#define P1_GRID (P1_T_BLOCKS + P1_G_BLOCKS + P1_H_BLOCKS)
// prep2 grid: block 0 scan, blocks [1, 1+100*2): sv build (512 bins per block, 2/thread)
#define P2_CHUNKS 2
#define P2_GRID (1 + 100 * P2_CHUNKS)

__device__ __forceinline__ float silu_f(float x) {
    return x / (1.0f + __expf(-x));
}

// ---------------- K1: prep1 — ai+T build | g-table (cooperative) | histogram ---------
__global__ __launch_bounds__(256) void prep1_kernel(
        const float* __restrict__ emb,
        const float* __restrict__ fw1, const float* __restrict__ fb1,
        const float* __restrict__ fw2, const float* __restrict__ fb2,
        const float* __restrict__ fw3, const float* __restrict__ fb3,
        const float* __restrict__ fc_w1, const float* __restrict__ fc_w2,
        const float* __restrict__ fc_w3, const float* __restrict__ fc_w4,
        const int* __restrict__ edst,
        float* __restrict__ T, float* __restrict__ g_tT,
        int* __restrict__ cnt_i) {
    __shared__ float smem[4096];        // T-branch uses 1040; g-branch uses 4096
    int b = blockIdx.x;
    int tid = threadIdx.x;

    if (b < P1_T_BLOCKS) {
        // ---- inline node-type MLP (10 types) then T[pair][k][12] build ----
        float* h1s = smem;              // [10][64]
        float* h2s = smem + 640;        // [10][32]
        float* ai  = smem + 960;        // [10][8]
        for (int idx = tid; idx < 640; idx += 256) {
            int t = idx >> 6, j = idx & 63;
            float acc = fb1[j];
            #pragma unroll
            for (int i = 0; i < 16; i++) acc += emb[t * 16 + i] * fw1[i * 64 + j];
            h1s[idx] = silu_f(acc);
        }
        __syncthreads();
        for (int idx = tid; idx < 320; idx += 256) {
            int t = idx >> 5, j = idx & 31;
            float acc = fb2[j];
            #pragma unroll
            for (int i = 0; i < 64; i++) acc += h1s[t * 64 + i] * fw2[i * 32 + j];
            h2s[idx] = silu_f(acc);
        }
        __syncthreads();
        if (tid < 80) {
            int t = tid >> 3, j = tid & 7;
            float acc = fb3[j];
            #pragma unroll
            for (int i = 0; i < 32; i++) acc += h2s[t * 32 + i] * fw3[i * 8 + j];
            ai[tid] = acc;
        }
        __syncthreads();

        int idx = b * 256 + tid;        // 6400 = 100 pairs x 64 k
        int pair = idx >> 6;
        int k = idx & 63;
        int ts = pair / 10, td = pair - ts * 10;
        float a[8], bb[8];
        #pragma unroll
        for (int i = 0; i < 8; i++) a[i] = ai[ts * 8 + i];
        #pragma unroll
        for (int i = 0; i < 8; i++) bb[i] = ai[td * 8 + i];
        float sv[12];
        #pragma unroll
        for (int i = 0; i < 12; i++) sv[i] = 0.0f;
        const float* wk = fc_w4 + k * 768;
        #pragma unroll 2
        for (int u = 0; u < 8; u++) {
            #pragma unroll
            for (int v = 0; v < 8; v++) {
                float ab = a[u] * bb[v];
                const float* wp = wk + u * 32 + v * 4;
                float4 w0 = *(const float4*)(wp);
                float4 w1 = *(const float4*)(wp + 256);
                float4 w2 = *(const float4*)(wp + 512);
                sv[0] += ab * w0.x; sv[1] += ab * w0.y; sv[2]  += ab * w0.z; sv[3]  += ab * w0.w;
                sv[4] += ab * w1.x; sv[5] += ab * w1.y; sv[6]  += ab * w1.z; sv[7]  += ab * w1.w;
                sv[8] += ab * w2.x; sv[9] += ab * w2.y; sv[10] += ab * w2.z; sv[11] += ab * w2.w;
            }
        }
        float* tp = T + pair * 768 + k * 12;
        #pragma unroll
        for (int j = 0; j < 12; j++) tp[j] = sv[j];
    } else if (b < P1_T_BLOCKS + P1_G_BLOCKS) {
        // ---- g-table, cooperative: 64 bins/block (lane=bin), wave owns 16 channels ----
        int lane = tid & 63;
        int wq = __builtin_amdgcn_readfirstlane(tid >> 6);
        int bin = (b - P1_T_BLOCKS) * 64 + lane;
        bool valid = (bin <= NBINS);
        float r = (float)bin * (RMAX / (float)NBINS);

        float rb[16];
        const float step = 5.0f / 17.0f;
        const float istep = 17.0f / 5.0f;
        const float rsc = 4.0f / 1.12f;
        #pragma unroll
        for (int i = 0; i < 16; i++) {
            float dd = (r - (float)(i + 1) * step) * istep;
            rb[i] = __expf(-dd * dd) * rsc;
        }

        // L1: 16 -> 64 (weight addresses wave-uniform -> scalar loads)
        #pragma unroll
        for (int jj = 0; jj < 16; jj++) {
            int j = wq * 16 + jj;
            float a0 = 0, a1 = 0, a2 = 0, a3 = 0;
            #pragma unroll
            for (int i = 0; i < 16; i += 4) {
                a0 += rb[i]     * fc_w1[(i)     * 64 + j];
                a1 += rb[i + 1] * fc_w1[(i + 1) * 64 + j];
                a2 += rb[i + 2] * fc_w1[(i + 2) * 64 + j];
                a3 += rb[i + 3] * fc_w1[(i + 3) * 64 + j];
            }
            smem[j * 64 + lane] = silu_f(((a0 + a1) + (a2 + a3)) * 0.25f);
        }
        __syncthreads();

        // L2: 64 -> 64
        float acc[16];
        #pragma unroll
        for (int jj = 0; jj < 16; jj++) acc[jj] = 0.0f;
        #pragma unroll
        for (int c = 0; c < 4; c++) {
            float hc[16];
            #pragma unroll
            for (int i = 0; i < 16; i++) hc[i] = smem[(c * 16 + i) * 64 + lane];
            #pragma unroll
            for (int jj = 0; jj < 16; jj++) {
                int j = wq * 16 + jj;
                #pragma unroll
                for (int i = 0; i < 16; i++) acc[jj] += hc[i] * fc_w2[(c * 16 + i) * 64 + j];
            }
        }
        __syncthreads();
        #pragma unroll
        for (int jj = 0; jj < 16; jj++) smem[(wq * 16 + jj) * 64 + lane] = silu_f(acc[jj] * 0.125f);
        __syncthreads();

        // L3: 64 -> 64 -> g_tT[k][bin] (lane-coalesced stores)
        #pragma unroll
        for (int jj = 0; jj < 16; jj++) acc[jj] = 0.0f;
        #pragma unroll
        for (int c = 0; c < 4; c++) {
            float hc[16];
            #pragma unroll
            for (int i = 0; i < 16; i++) hc[i] = smem[(c * 16 + i) * 64 + lane];
            #pragma unroll
            for (int jj = 0; jj < 16; jj++) {
                int j = wq * 16 + jj;
                #pragma unroll
                for (int i = 0; i < 16; i++) acc[jj] += hc[i] * fc_w3[(c * 16 + i) * 64 + j];
            }
        }
        if (valid) {
            #pragma unroll
            for (int jj = 0; jj < 16; jj++)
                g_tT[(size_t)(wq * 16 + jj) * BINS1 + bin] = silu_f(acc[jj] * 0.125f);
        }
    } else {
        // ---- histogram of edge_dst ----
        int e = (b - P1_T_BLOCKS - P1_G_BLOCKS) * 256 + tid;
        if (e < N_EDGES) atomicAdd(&cnt_i[edst[e]], 1);
    }
}

// ---------------- K2: prep2 — scan (block 0) | sv_table = (1/64) g @ T ---------------
__global__ __launch_bounds__(256) void prep2_kernel(
        const int* __restrict__ cnt_i, int* __restrict__ node_off,
        const float* __restrict__ T, const float* __restrict__ g_tT,
        float* __restrict__ sv_table) {
    __shared__ int part[256];
    int b = blockIdx.x;
    int tid = threadIdx.x;

    if (b == 0) {
        int base = tid * 79;            // 256 * 79 >= 20000
        int s = 0;
        for (int i = 0; i < 79; i++) {
            int n = base + i;
            if (n < N_NODES) s += cnt_i[n];
        }
        part[tid] = s;
        __syncthreads();
        for (int off = 1; off < 256; off <<= 1) {
            int v = part[tid];
            int add = (tid >= off) ? part[tid - off] : 0;
            __syncthreads();
            part[tid] = v + add;
            __syncthreads();
        }
        int run = (tid == 0) ? 0 : part[tid - 1];
        for (int i = 0; i < 79; i++) {
            int n = base + i;
            if (n < N_NODES) { node_off[n] = run; run += cnt_i[n]; }
        }
        if (tid == 255) node_off[N_NODES] = part[255];
        return;
    }

    int idx = b - 1;
    int pair = idx / P2_CHUNKS;
    int chunk = idx - pair * P2_CHUNKS;
    int b0 = chunk * 512 + tid;
    int b1 = b0 + 256;
    bool v0 = (b0 <= NBINS), v1 = (b1 <= NBINS);
    int rb0 = v0 ? b0 : NBINS;          // clamp to stay in-bounds
    int rb1 = v1 ? b1 : NBINS;

    float acc0[12], acc1[12];
    #pragma unroll
    for (int j = 0; j < 12; j++) { acc0[j] = 0.0f; acc1[j] = 0.0f; }
    const float* Tp = T + pair * 768;
    #pragma unroll 4
    for (int k = 0; k < 64; k++) {
        float g0 = g_tT[(size_t)k * BINS1 + rb0];  // two independent coalesced streams
        float g1 = g_tT[(size_t)k * BINS1 + rb1];
        const float* tr = Tp + k * 12;             // pair uniform per block -> s_load
        float4 t0 = *(const float4*)(tr);
        float4 t1 = *(const float4*)(tr + 4);
        float4 t2 = *(const float4*)(tr + 8);
        acc0[0] += g0 * t0.x; acc0[1] += g0 * t0.y; acc0[2]  += g0 * t0.z; acc0[3]  += g0 * t0.w;
        acc0[4] += g0 * t1.x; acc0[5] += g0 * t1.y; acc0[6]  += g0 * t1.z; acc0[7]  += g0 * t1.w;
        acc0[8] += g0 * t2.x; acc0[9] += g0 * t2.y; acc0[10] += g0 * t2.z; acc0[11] += g0 * t2.w;
        acc1[0] += g1 * t0.x; acc1[1] += g1 * t0.y; acc1[2]  += g1 * t0.z; acc1[3]  += g1 * t0.w;
        acc1[4] += g1 * t1.x; acc1[5] += g1 * t1.y; acc1[6]  += g1 * t1.z; acc1[7]  += g1 * t1.w;
        acc1[8] += g1 * t2.x; acc1[9] += g1 * t2.y; acc1[10] += g1 * t2.z; acc1[11] += g1 * t2.w;
    }
    const float isc = 1.0f / 64.0f;
    if (v0) {
        float* o = sv_table + ((size_t)pair * BINS1 + b0) * 12;
        #pragma unroll
        for (int j = 0; j < 12; j++) o[j] = acc0[j] * isc;
    }
    if (v1) {
        float* o = sv_table + ((size_t)pair * BINS1 + b1) * 12;
        #pragma unroll
        for (int j = 0; j < 12; j++) o[j] = acc1[j] * isc;
    }
}

// ---------------- K3: edge kernel — dual-edge ILP, self-assigned CSR slot ------------
__global__ __launch_bounds__(256) void edge_table_kernel(
        const float* __restrict__ pos, const int* __restrict__ batch,
        const int* __restrict__ esrc, const int* __restrict__ edst,
        const float* __restrict__ shifts, const float* __restrict__ cell,
        const int* __restrict__ A,
        const int* __restrict__ node_off, int* __restrict__ node_cur,
        const float* __restrict__ sv_table, float* __restrict__ ef) {
    int g = blockIdx.x * 256 + threadIdx.x;
    if (g >= EHALF) return;
    int eArr[2] = { g, g + EHALF };              // two coalesced streams

    #pragma unroll
    for (int sub = 0; sub < 2; sub++) {          // unrolled: compiler interleaves both streams
        int e = eArr[sub];
        int s = esrc[e], d = edst[e];
        int gb = batch[s];
        float t0 = shifts[e * 3 + 0], t1 = shifts[e * 3 + 1], t2 = shifts[e * 3 + 2];
        const float* C = cell + gb * 9;
        float shx = t0 * C[0] + t1 * C[3] + t2 * C[6];
        float shy = t0 * C[1] + t1 * C[4] + t2 * C[7];
        float shz = t0 * C[2] + t1 * C[5] + t2 * C[8];
        float ex = pos[d * 3 + 0] - pos[s * 3 + 0] + shx;
        float ey = pos[d * 3 + 1] - pos[s * 3 + 1] + shy;
        float ez = pos[d * 3 + 2] - pos[s * 3 + 2] + shz;
        float r = sqrtf(ex * ex + ey * ey + ez * ez);
        float inv = 1.0f / fmaxf(r, 1e-9f);
        float x = ex * inv, y = ey * inv, z = ez * inv;

        float sv[12];
        if (r >= RMAX) {
            #pragma unroll
            for (int j = 0; j < 12; j++) sv[j] = 0.0f;
        } else {
            int pair = A[s] * 10 + A[d];
            float t = r * ((float)NBINS / RMAX);
            int i = (int)t;
            i = (i > NBINS - 1) ? (NBINS - 1) : i;
            float f = t - (float)i;
            const float* r0 = sv_table + ((size_t)pair * BINS1 + i) * 12;  // 96B contiguous, L2
            #pragma unroll
            for (int j = 0; j < 12; j++) {
                float lo = r0[j], hi = r0[12 + j];
                sv[j] = lo + f * (hi - lo);
            }
        }

        const float S3  = 1.7320508075688772f;
        const float S15 = 3.8729833462074170f;
        const float S5  = 2.2360679774997896f;
        float sh1v[3] = { S3 * y, S3 * z, S3 * x };
        float sh2v[5] = { S15 * x * y, S15 * y * z, 0.5f * S5 * (3.0f * z * z - 1.0f),
                          S15 * x * z, 0.5f * S15 * (x * x - y * y) };

        float o[36];
        #pragma unroll
        for (int w = 0; w < 4; w++) o[w] = sv[w];
        #pragma unroll
        for (int w = 0; w < 4; w++) {
            float sw = sv[4 + w];
            #pragma unroll
            for (int j = 0; j < 3; j++) o[4 + w * 3 + j] = sw * sh1v[j];
        }
        #pragma unroll
        for (int w = 0; w < 4; w++) {
            float sw = sv[8 + w];
            #pragma unroll
            for (int j = 0; j < 5; j++) o[16 + w * 5 + j] = sw * sh2v[j];
        }

        // self-assigned slot within the node's CSR segment; ef stays node-grouped
        int slot = atomicAdd(&node_cur[d], 1);
        int p = node_off[d] + slot;
        float4* dst = (float4*)(ef + (size_t)p * 36);   // 144B = 9 x float4, aligned
        #pragma unroll
        for (int q = 0; q < 9; q++) dst[q] = ((float4*)o)[q];
    }
}

// ---------------- K4: gather + mean (float4 stream per node, 2x unrolled) ------------
__global__ void gather_kernel(const float* __restrict__ ef,
                              const int* __restrict__ node_off,
                              float* __restrict__ out) {
    int idx = blockIdx.x * 256 + threadIdx.x;   // (node, float4-group)
    if (idx >= N_NODES * 9) return;
    int n = idx / 9;
    int g = idx - n * 9;
    int beg = node_off[n], end = node_off[n + 1];
    const float4* ef4 = (const float4*)ef;
    float4 s0 = make_float4(0.f, 0.f, 0.f, 0.f);
    float4 s1 = make_float4(0.f, 0.f, 0.f, 0.f);
    int p = beg;
    for (; p + 1 < end; p += 2) {               // two loads in flight per iteration
        float4 v0 = ef4[(size_t)p * 9 + g];
        float4 v1 = ef4[(size_t)(p + 1) * 9 + g];
        s0.x += v0.x; s0.y += v0.y; s0.z += v0.z; s0.w += v0.w;
        s1.x += v1.x; s1.y += v1.y; s1.z += v1.z; s1.w += v1.w;
    }
    if (p < end) {
        float4 v = ef4[(size_t)p * 9 + g];
        s0.x += v.x; s0.y += v.y; s0.z += v.z; s0.w += v.w;
    }
    float c = 1.0f / fmaxf((float)(end - beg), 1.0f);
    ((float4*)out)[idx] = make_float4((s0.x + s1.x) * c, (s0.y + s1.y) * c,
                                      (s0.z + s1.z) * c, (s0.w + s1.w) * c);
}

extern "C" void kernel_launch(void* const* d_in, const int* in_sizes, int n_in,
                              void* d_out, int out_size, void* d_ws, size_t ws_size,
                              hipStream_t stream) {
    const float* pos    = (const float*)d_in[0];
    const int*   A      = (const int*)d_in[1];
    const int*   batch  = (const int*)d_in[2];
    const int*   esrc   = (const int*)d_in[3];
    const int*   edst   = (const int*)d_in[4];
    const float* shifts = (const float*)d_in[5];
    const float* cell   = (const float*)d_in[6];
    const float* emb    = (const float*)d_in[7];
    const float* fw1    = (const float*)d_in[8];
    const float* fb1    = (const float*)d_in[9];
    const float* fw2    = (const float*)d_in[10];
    const float* fb2    = (const float*)d_in[11];
    const float* fw3    = (const float*)d_in[12];
    const float* fb3    = (const float*)d_in[13];
    const float* fcw1   = (const float*)d_in[14];
    const float* fcw2   = (const float*)d_in[15];
    const float* fcw3   = (const float*)d_in[16];
    const float* fcw4   = (const float*)d_in[17];
    float* out = (float*)d_out;

    char* ws = (char*)d_ws;
    float* ef      = (float*)(ws + OFF_EF);
    float* T       = (float*)(ws + OFF_T);
    float* g_tT    = (float*)(ws + OFF_G);
    float* sv_table= (float*)(ws + OFF_SV);
    int*   node_off= (int*)(ws + OFF_NOFF);
    int*   cnt_i   = (int*)(ws + OFF_NCNT);
    int*   node_cur= (int*)(ws + OFF_NCUR);

    hipMemsetAsync(cnt_i, 0, (size_t)2 * N_NODES * 4, stream);

    prep1_kernel<<<P1_GRID, 256, 0, stream>>>(emb, fw1, fb1, fw2, fb2, fw3, fb3,
                                              fcw1, fcw2, fcw3, fcw4, edst,
                                              T, g_tT, cnt_i);
    prep2_kernel<<<P2_GRID, 256, 0, stream>>>(cnt_i, node_off, T, g_tT, sv_table);
    edge_table_kernel<<<(EHALF + 255) / 256, 256, 0, stream>>>(
        pos, batch, esrc, edst, shifts, cell, A, node_off, node_cur, sv_table, ef);
    gather_kernel<<<(N_NODES * 9 + 255) / 256, 256, 0, stream>>>(ef, node_off, out);
}